// Round 1
// 280.334 us; speedup vs baseline: 1.0298x; 1.0298x over previous
//
#include <hip/hip_runtime.h>

// ---- problem constants ----
#define D_MODEL 1024
#define NHEAD   16
#define DK      64
#define BATCH   2
#define SEQ     2048

typedef __attribute__((ext_vector_type(8))) short bf16x8;
typedef __attribute__((ext_vector_type(4))) short bf16x4;
typedef __attribute__((ext_vector_type(4))) float f32x4;
typedef __attribute__((ext_vector_type(2))) int i32x2;

#define QSCALE 0.18033688011f   // log2(e) / sqrt(64): folded into Q projection

__device__ __forceinline__ unsigned short f2b(float x) {
  unsigned u = __builtin_bit_cast(unsigned, x);
  u = (u + 0x7fffu + ((u >> 16) & 1u)) >> 16;   // RNE to bf16
  return (unsigned short)u;
}
// round-half-up bf16 (bias 2^-17 rel, error <= 2^-9 like RNE) -- 1 add
__device__ __forceinline__ unsigned short f2b_rhu(float x) {
  return (unsigned short)((__builtin_bit_cast(unsigned, x) + 0x8000u) >> 16);
}
// pack two fp32 -> two bf16 (round-half-up) in 3 VALU: add, add, v_perm
__device__ __forceinline__ int pk2(float a, float b) {
  unsigned ua = __builtin_bit_cast(unsigned, a) + 0x8000u;
  unsigned ub = __builtin_bit_cast(unsigned, b) + 0x8000u;
  return (int)__builtin_amdgcn_perm(ub, ua, 0x07060302u);  // [ub.hi16 : ua.hi16]
}
// same on raw (already-masked) fp32 bit patterns
__device__ __forceinline__ int pk2u(unsigned ua, unsigned ub) {
  return (int)__builtin_amdgcn_perm(ub + 0x8000u, ua + 0x8000u, 0x07060302u);
}

// async 16B global->LDS (m97 pattern). LDS dest = wave-uniform base + lane*16.
typedef const __attribute__((address_space(1))) void* gas_p;
typedef __attribute__((address_space(3))) void* las_p;
__device__ __forceinline__ void gll16(const void* g, void* l) {
  __builtin_amdgcn_global_load_lds((gas_p)g, (las_p)l, 16, 0, 0);
}

// 16x16x16 bf16 MFMA (K=16: A-frag k = quad*4+j, matching swapped-S C-layout)
__device__ __forceinline__ f32x4 mfma16(bf16x4 a, bf16x4 b, f32x4 c) {
#if __has_builtin(__builtin_amdgcn_mfma_f32_16x16x16bf16_1k)
  return __builtin_amdgcn_mfma_f32_16x16x16bf16_1k(a, b, c, 0, 0, 0);
#else
  f32x4 d;
  asm("v_mfma_f32_16x16x16_bf16 %0, %1, %2, %3" : "=v"(d) : "v"(a), "v"(b), "v"(c));
  return d;
#endif
}

// ---- cast q,k,v fp32 -> bf16 (qb/kb live in d_out scratch, vb in ws) ----
__global__ __launch_bounds__(256) void cast3_kernel(
    const float* __restrict__ q, const float* __restrict__ k, const float* __restrict__ v,
    unsigned short* __restrict__ qb, unsigned short* __restrict__ kb,
    unsigned short* __restrict__ vb) {
  const float* src = blockIdx.y == 0 ? q : (blockIdx.y == 1 ? k : v);
  unsigned short* dst = blockIdx.y == 0 ? qb : (blockIdx.y == 1 ? kb : vb);
  size_t i = ((size_t)blockIdx.x * 256 + threadIdx.x) * 8;
  float4 x0 = *(const float4*)&src[i];
  float4 x1 = *(const float4*)&src[i + 4];
  int4 w;
  w.x = pk2(x0.x, x0.y); w.y = pk2(x0.z, x0.w);
  w.z = pk2(x1.x, x1.y); w.w = pk2(x1.z, x1.w);
  *(int4*)&dst[i] = w;
}

// ---- transpose + cast weights: w[in][out] fp32 -> wt[out][in] bf16 ----
__global__ __launch_bounds__(256) void wtrans_kernel(
    const float* __restrict__ wq, const float* __restrict__ wk,
    const float* __restrict__ wv, const float* __restrict__ wf,
    unsigned short* __restrict__ wqt, unsigned short* __restrict__ wkt,
    unsigned short* __restrict__ wvt, unsigned short* __restrict__ wft) {
  __shared__ float tile[64][65];
  const float* w; unsigned short* wt;
  switch (blockIdx.z) {
    case 0: w = wq; wt = wqt; break;
    case 1: w = wk; wt = wkt; break;
    case 2: w = wv; wt = wvt; break;
    default: w = wf; wt = wft; break;
  }
  int r0 = blockIdx.y * 64, c0 = blockIdx.x * 64;
  int t = threadIdx.x;
  for (int i = 0; i < 16; ++i) {
    int idx = t + i * 256; int r = idx >> 6, c = idx & 63;
    tile[r][c] = w[(size_t)(r0 + r) * D_MODEL + c0 + c];
  }
  __syncthreads();
  for (int i = 0; i < 16; ++i) {
    int idx = t + i * 256; int r = idx >> 6, c = idx & 63;
    wt[(size_t)(c0 + r) * D_MODEL + r0 + c] = f2b(tile[c][r]);
  }
}

// ---- pack mask int32 -> bit-words (bit lane = mask!=0), one u64 per 64 keys ----
__global__ __launch_bounds__(256) void maskpack_kernel(
    const int* __restrict__ mask, unsigned long long* __restrict__ mbits) {
  size_t gw = ((size_t)blockIdx.x * 256 + threadIdx.x) >> 6;
  int lane = threadIdx.x & 63;
  int val = mask[gw * 64 + lane];
  unsigned long long bits = __ballot(val != 0);
  if (lane == 0) mbits[gw] = bits;
}

// ---- fused QKV projection GEMM: 128x128 tile, BK=32, DOUBLE-BUFFERED
// async staging with ONE barrier per iteration: DMA for chunk it+1 is issued
// right after the barrier opening iteration it, and drained a full compute
// phase later by the next barrier. ----
__global__ __launch_bounds__(256) void gemm_qkv_kernel(
    const unsigned short* __restrict__ qb, const unsigned short* __restrict__ kb,
    const unsigned short* __restrict__ vb,
    const unsigned short* __restrict__ wqt, const unsigned short* __restrict__ wkt,
    const unsigned short* __restrict__ wvt,
    const float* __restrict__ bq, const float* __restrict__ bv,
    unsigned short* __restrict__ qh, unsigned short* __restrict__ kh,
    unsigned short* __restrict__ vt) {
  // buffers: buf b at b*8192 (As at +0, Bs at +4096, each 128 rows x 32 cols);
  // V-transpose epilogue aliases the whole 16640-short region.
  __shared__ unsigned short SB[16640];
  int bid = blockIdx.x;
  int xcd = bid & 7, slot = bid >> 3;      // 96 slots per XCD
  int mi = slot & 3, zn = slot >> 2;       // 4 m-panels per XCD, zn in [0,24)
  int z = zn >> 3;
  int n0 = (zn & 7) * 128;
  int m0 = (mi * 8 + xcd) * 128;
  const unsigned short* A; const unsigned short* Bt;
  switch (z) {
    case 0:  A = qb; Bt = wqt; break;
    case 1:  A = kb; Bt = wkt; break;
    default: A = vb; Bt = wvt; break;
  }
  int t = threadIdx.x, lane = t & 63, wave = t >> 6;
  int l16 = lane & 15, quad = lane >> 4;
  int wm = (wave & 1) * 64, wn = (wave >> 1) * 64;
  f32x4 zero = {0.f, 0.f, 0.f, 0.f};
  f32x4 acc[4][4];
  for (int mt = 0; mt < 4; ++mt) for (int nt = 0; nt < 4; ++nt) acc[mt][nt] = zero;

  int drow = lane >> 2, dcol = (lane & 3) * 8;
  const unsigned short* asrc = A  + (size_t)(m0 + wave * 32 + drow) * D_MODEL + dcol;
  const unsigned short* bsrc = Bt + (size_t)(n0 + wave * 32 + drow) * D_MODEL + dcol;
  int dst = wave * 1024 + lane * 8;        // within-buffer wave slice (+g*512)

  // prologue: chunk 0 -> buf0
#pragma unroll
  for (int g = 0; g < 2; ++g) {
    gll16(asrc + (size_t)(g * 16) * D_MODEL, &SB[dst + g * 512]);
    gll16(bsrc + (size_t)(g * 16) * D_MODEL, &SB[4096 + dst + g * 512]);
  }
  for (int it = 0; it < 32; ++it) {
    __syncthreads();                       // drains chunk it's DMAs
    if (it + 1 < 32) {
      int nb = ((it + 1) & 1) * 8192, kn = (it + 1) * 32;
#pragma unroll
      for (int g = 0; g < 2; ++g) {
        gll16(asrc + (size_t)(g * 16) * D_MODEL + kn, &SB[nb + dst + g * 512]);
        gll16(bsrc + (size_t)(g * 16) * D_MODEL + kn, &SB[nb + 4096 + dst + g * 512]);
      }
    }
    int cb = (it & 1) * 8192;
    bf16x8 a[4], b[4];
    for (int mt = 0; mt < 4; ++mt)
      a[mt] = *(const bf16x8*)&SB[cb + (wm + mt * 16 + l16) * 32 + quad * 8];
    for (int nt = 0; nt < 4; ++nt)
      b[nt] = *(const bf16x8*)&SB[cb + 4096 + (wn + nt * 16 + l16) * 32 + quad * 8];
    for (int mt = 0; mt < 4; ++mt)
      for (int nt = 0; nt < 4; ++nt)
        acc[mt][nt] = __builtin_amdgcn_mfma_f32_16x16x32_bf16(a[mt], b[nt], acc[mt][nt], 0, 0, 0);
  }

  if (z == 2) {
    __syncthreads();
#pragma unroll
    for (int nt = 0; nt < 4; ++nt) {
      int col = wn + nt * 16 + l16;
      float bb = bv[n0 + col];
      for (int mt = 0; mt < 4; ++mt)
        for (int r = 0; r < 4; ++r)
          SB[col * 130 + wm + mt * 16 + quad * 4 + r] = f2b_rhu(acc[mt][nt][r] + bb);
    }
    __syncthreads();
    int c = t >> 1, hf = t & 1;
    int colg = n0 + c, hh = colg >> 6, dd = colg & 63;
    int b_ = m0 >> 11, sbase = m0 & (SEQ - 1);
    unsigned short* dstp = vt + (((size_t)(b_ * NHEAD + hh)) * DK + dd) * SEQ + sbase + hf * 64;
#pragma unroll
    for (int j = 0; j < 8; ++j)
      *(int4*)(dstp + j * 8) = *(const int4*)&SB[c * 130 + hf * 64 + j * 8];
  } else if (z == 0) {
    for (int nt = 0; nt < 4; ++nt) {
      int col = n0 + wn + nt * 16 + l16;
      float bb = bq[col];
      int h = col >> 6, d = col & 63;
      for (int mt = 0; mt < 4; ++mt)
        for (int r = 0; r < 4; ++r) {
          int row = m0 + wm + mt * 16 + quad * 4 + r;
          int b_ = row >> 11, s = row & (SEQ - 1);
          qh[(((size_t)(b_ * NHEAD + h) * SEQ) + s) * DK + d] =
              f2b_rhu((acc[mt][nt][r] + bb) * QSCALE);
        }
    }
  } else {
    for (int nt = 0; nt < 4; ++nt) {
      int col = n0 + wn + nt * 16 + l16;
      int h = col >> 6, d = col & 63;
      for (int mt = 0; mt < 4; ++mt)
        for (int r = 0; r < 4; ++r) {
          int row = m0 + wm + mt * 16 + quad * 4 + r;
          int b_ = row >> 11, s = row & (SEQ - 1);
          kh[(((size_t)(b_ * NHEAD + h) * SEQ) + s) * DK + d] = f2b_rhu(acc[mt][nt][r]);
        }
    }
  }
}

// ---- output projection GEMM: 64x64 tiles, BK=64 double-buffered,
// one barrier per iteration (same issue-early/drain-late scheme). ----
__global__ __launch_bounds__(256) void gemm_out_kernel(
    const unsigned short* __restrict__ A, const unsigned short* __restrict__ Bt,
    const float* __restrict__ bias, float* __restrict__ out) {
  __shared__ unsigned short As[8192], Bs[8192];   // buf b at b*4096, halves at +0,+2048
  int bid = blockIdx.x;
  int xcd = bid & 7, slot = bid >> 3;
  int mi = slot & 7, n0 = (slot >> 3) * 64;
  int m0 = (mi * 8 + xcd) * 64;
  int t = threadIdx.x, lane = t & 63, wave = t >> 6;
  int l16 = lane & 15, quad = lane >> 4;
  int wm = (wave & 1) * 32, wn = (wave >> 1) * 32;
  f32x4 zero = {0.f, 0.f, 0.f, 0.f};
  f32x4 acc[2][2];
  for (int mt = 0; mt < 2; ++mt) for (int nt = 0; nt < 2; ++nt) acc[mt][nt] = zero;

  int drow = lane >> 2, dcol = (lane & 3) * 8;
  const unsigned short* asrc = A  + (size_t)(m0 + wave * 16 + drow) * D_MODEL + dcol;
  const unsigned short* bsrc = Bt + (size_t)(n0 + wave * 16 + drow) * D_MODEL + dcol;
  int dst = wave * 512 + lane * 8;

#pragma unroll
  for (int hf = 0; hf < 2; ++hf) {
    gll16(asrc + hf * 32, &As[dst + hf * 2048]);
    gll16(bsrc + hf * 32, &Bs[dst + hf * 2048]);
  }
  for (int it = 0; it < 16; ++it) {
    __syncthreads();
    if (it + 1 < 16) {
      int nb = ((it + 1) & 1) * 4096, kn = (it + 1) * 64;
#pragma unroll
      for (int hf = 0; hf < 2; ++hf) {
        gll16(asrc + kn + hf * 32, &As[nb + dst + hf * 2048]);
        gll16(bsrc + kn + hf * 32, &Bs[nb + dst + hf * 2048]);
      }
    }
    int cb = (it & 1) * 4096;
#pragma unroll
    for (int half = 0; half < 2; ++half) {
      bf16x8 a[2], b[2];
      for (int mt = 0; mt < 2; ++mt)
        a[mt] = *(const bf16x8*)&As[cb + half * 2048 + (wm + mt * 16 + l16) * 32 + quad * 8];
      for (int nt = 0; nt < 2; ++nt)
        b[nt] = *(const bf16x8*)&Bs[cb + half * 2048 + (wn + nt * 16 + l16) * 32 + quad * 8];
      for (int mt = 0; mt < 2; ++mt)
        for (int nt = 0; nt < 2; ++nt)
          acc[mt][nt] = __builtin_amdgcn_mfma_f32_16x16x32_bf16(a[mt], b[nt], acc[mt][nt], 0, 0, 0);
    }
  }
  for (int nt = 0; nt < 2; ++nt) {
    int col = n0 + wn + nt * 16 + l16;
    float bb = bias[col];
    for (int mt = 0; mt < 2; ++mt)
      for (int r = 0; r < 4; ++r) {
        int row = m0 + wm + mt * 16 + quad * 4 + r;
        out[(size_t)row * D_MODEL + col] = acc[mt][nt][r] + bb;
      }
  }
}

// ---- flash attention, REGISTER-SOFTMAX rewrite (R10) ----
// Structural changes vs previous version:
//  * S computed TRANSPOSED: accS = mfma_16x16x32(K_frag, Q_frag). C-layout then
//    gives each lane one q-row (q = l16) with k = nt*16 + quad*4 + r -- which is
//    exactly the A-operand layout of v_mfma_f32_16x16x16_bf16 (k = quad*4 + j).
//    So masked exp2 scores pack in-register straight into PV A-frags: the P LDS
//    tile, its 16 ds_write_b16 + strided reads, all 8.4M bank conflicts, and the
//    mid-iteration barrier are GONE. Row sums keep the ones-MFMA trick; accO /
//    accRS come out in the same (row=quad*4+r, col=l16) layout as before, so the
//    epilogue is unchanged.
//  * 32 q-rows per wave (2 independent 16-row fragment sets): K/V LDS reads are
//    shared across both, halving LDS-pipe traffic per unit of work (it was the
//    ~40us floor). Grid 1024 -> 512 blocks (2 blocks/CU, 64KB of 160KB LDS).
//  * K AND V double-buffered, ONE __syncthreads per kv-iter (was 2): both tiles
//    are staged a full iteration ahead, so the barrier's vmcnt(0) drain is free.
//  * LDS tiles are [64][64] shorts (128B rows) with 16B-chunk XOR swizzle
//    (chunk ^= row&7): conflict-free for both the b128 K-frag reads and the b64
//    V-frag reads. Swizzle applied on the STAGING SIDE by pre-swizzling the
//    global source address (gll16's LDS dest must stay linear), and on the read
//    side by the same XOR folded into per-lane loop-invariant base addresses.
__global__ __launch_bounds__(256, 2) void attn_kernel(
    const unsigned short* __restrict__ qh, const unsigned short* __restrict__ kh,
    const unsigned short* __restrict__ vt, const unsigned long long* __restrict__ mbits,
    unsigned short* __restrict__ attb) {
  __shared__ unsigned short Ks[8192];   // 2 bufs x [64 k-rows][64 d], swizzled
  __shared__ unsigned short Vs[8192];   // 2 bufs x [64 d-rows][64 s], swizzled
  int bid = blockIdx.x;
  int xcd = bid & 7, slot = bid >> 3;   // 64 slots per XCD
  int bh_ = 4 * xcd + (slot >> 4);      // 4 bh per XCD (KV L2 locality)
  int qt = slot & 15;                   // 16 q-tiles of 128 rows
  int b = bh_ >> 4, h = bh_ & 15;
  int t = threadIdx.x, lane = t & 63, wave = t >> 6;
  int l16 = lane & 15, quad = lane >> 4;
  size_t bh = (size_t)b * NHEAD + h;

  const unsigned short* Kg = kh + bh * SEQ * DK;
  const unsigned short* Vg = vt + bh * DK * SEQ;
  const unsigned long long* mrow = mbits + (size_t)b * SEQ * (SEQ / 64);

  // Q fragments straight from global (B-operand; row = q = l16, elems d)
  bf16x8 qf[2][2];
#pragma unroll
  for (int qm = 0; qm < 2; ++qm) {
    const unsigned short* Qg =
        qh + (bh * SEQ + (size_t)(qt * 128 + wave * 32 + qm * 16 + l16)) * DK;
    qf[qm][0] = *(const bf16x8*)&Qg[quad * 8];
    qf[qm][1] = *(const bf16x8*)&Qg[32 + quad * 8];
  }

  // staging: one gll16 covers 8 rows x 64 shorts; lane -> (row = lane>>3,
  // chunk = lane&7). Global source chunk pre-swizzled: c = (lane&7) ^ (row&7).
  int srow = lane >> 3;
  int schk = ((lane & 7) ^ (srow & 7)) * 8;   // shorts
  const unsigned short* ks0 = Kg + (size_t)(wave * 16 + srow) * DK + schk;
  const unsigned short* ks1 = Kg + (size_t)(wave * 16 + 8 + srow) * DK + schk;
  const unsigned short* vs0 = Vg + (size_t)(wave * 16 + srow) * SEQ + schk;
  const unsigned short* vs1 = Vg + (size_t)(wave * 16 + 8 + srow) * SEQ + schk;
  int sdst = wave * 1024 + lane * 8;

  // per-lane loop-invariant LDS read bases (XOR swizzle folded in)
  int x7 = l16 & 7;
  int ka0 = l16 * 64 + ((quad ^ x7) * 8);            // step 0: d-chunk = quad
  int ka1 = l16 * 64 + (((4 + quad) ^ x7) * 8);      // step 1: d-chunk = 4+quad
  int va[4];
#pragma unroll
  for (int nt = 0; nt < 4; ++nt)
    va[nt] = l16 * 64 + (((nt * 2 + (quad >> 1)) ^ x7) * 8) + (quad & 1) * 4;

  bf16x4 ones4;
#pragma unroll
  for (int i = 0; i < 4; ++i) ones4[i] = (short)0x3F80;

  f32x4 zero = {0.f, 0.f, 0.f, 0.f};
  f32x4 accO[2][4], accRS[2];
#pragma unroll
  for (int qm = 0; qm < 2; ++qm) {
    accRS[qm] = zero;
    for (int dt = 0; dt < 4; ++dt) accO[qm][dt] = zero;
  }

  // prologue: K(0), V(0) -> buf0
  gll16(ks0, &Ks[sdst]);       gll16(ks1, &Ks[sdst + 512]);
  gll16(vs0, &Vs[sdst]);       gll16(vs1, &Vs[sdst + 512]);

  for (int tk = 0; tk < SEQ / 64; ++tk) {
    __syncthreads();     // drains K(tk)+V(tk); all waves done with buf tk+1 parity
    if (tk + 1 < SEQ / 64) {
      int nb = ((tk + 1) & 1) * 4096;
      size_t ko = (size_t)(tk + 1) * 64 * DK;
      int vo = (tk + 1) * 64;
      gll16(ks0 + ko, &Ks[nb + sdst]);  gll16(ks1 + ko, &Ks[nb + sdst + 512]);
      gll16(vs0 + vo, &Vs[nb + sdst]);  gll16(vs1 + vo, &Vs[nb + sdst + 512]);
    }
    int cb = (tk & 1) * 4096;

    // S^T = K . Q^T : lane's scores -> q = l16, k = nt*16 + quad*4 + r
    f32x4 accS[2][4];
#pragma unroll
    for (int qm = 0; qm < 2; ++qm)
      for (int nt = 0; nt < 4; ++nt) accS[qm][nt] = zero;
#pragma unroll
    for (int step = 0; step < 2; ++step) {
      int ka = step ? ka1 : ka0;
#pragma unroll
      for (int nt = 0; nt < 4; ++nt) {
        bf16x8 kf = *(const bf16x8*)&Ks[cb + ka + nt * 1024];
        accS[0][nt] = __builtin_amdgcn_mfma_f32_16x16x32_bf16(kf, qf[0][step], accS[0][nt], 0, 0, 0);
        accS[1][nt] = __builtin_amdgcn_mfma_f32_16x16x32_bf16(kf, qf[1][step], accS[1][nt], 0, 0, 0);
      }
    }

    // masked p = exp2(s), packed in-register into PV A-frags (k = quad*4 + j)
    bf16x4 ap[2][4];
#pragma unroll
    for (int qm = 0; qm < 2; ++qm) {
      int qrow = qt * 128 + wave * 32 + qm * 16 + l16;
      unsigned long long mq = mrow[(size_t)qrow * (SEQ / 64) + tk] >> (quad * 4);
      unsigned mlo = (unsigned)mq, mhi = (unsigned)(mq >> 32);
#pragma unroll
      for (int nt = 0; nt < 4; ++nt) {
        unsigned w = (nt < 2) ? mlo : mhi;
        unsigned pu[4];
#pragma unroll
        for (int r = 0; r < 4; ++r) {
          float pv = __builtin_amdgcn_exp2f(accS[qm][nt][r]);
          int msk = ((int)(w << (31 - ((nt & 1) * 16 + r)))) >> 31;   // v_bfe_i32
          pu[r] = __builtin_bit_cast(unsigned, pv) & (unsigned)msk;
        }
        i32x2 wv;
        wv[0] = pk2u(pu[0], pu[1]);
        wv[1] = pk2u(pu[2], pu[3]);
        ap[qm][nt] = __builtin_bit_cast(bf16x4, wv);
      }
      // row sums on the MFMA pipe (accumulates in same layout as accO)
#pragma unroll
      for (int nt = 0; nt < 4; ++nt)
        accRS[qm] = mfma16(ap[qm][nt], ones4, accRS[qm]);
    }

    // O += P V  (V frags shared across both q-fragment sets)
#pragma unroll
    for (int nt = 0; nt < 4; ++nt) {
      int vb_ = cb + va[nt];
#pragma unroll
      for (int dt = 0; dt < 4; ++dt) {
        bf16x4 vf = *(const bf16x4*)&Vs[vb_ + dt * 1024];
        accO[0][dt] = mfma16(ap[0][nt], vf, accO[0][dt]);
        accO[1][dt] = mfma16(ap[1][nt], vf, accO[1][dt]);
      }
    }
  }

#pragma unroll
  for (int qm = 0; qm < 2; ++qm)
    for (int r = 0; r < 4; ++r) {
      float sden = accRS[qm][r];
      float inv = sden > 0.f ? 1.f / sden : 0.f;
      int row = qt * 128 + wave * 32 + qm * 16 + quad * 4 + r;
      size_t ob = ((size_t)b * SEQ + row) * D_MODEL + (size_t)h * DK;
      for (int dt = 0; dt < 4; ++dt)
        attb[ob + dt * 16 + l16] = f2b_rhu(accO[qm][dt][r] * inv);
    }
}

extern "C" void kernel_launch(void* const* d_in, const int* in_sizes, int n_in,
                              void* d_out, int out_size, void* d_ws, size_t ws_size,
                              hipStream_t stream) {
  (void)in_sizes; (void)n_in; (void)out_size; (void)ws_size;
  const float* q    = (const float*)d_in[0];
  const float* k    = (const float*)d_in[1];
  const float* v    = (const float*)d_in[2];
  const int*   mask = (const int*)d_in[3];
  const float* wq   = (const float*)d_in[4];
  const float* bq   = (const float*)d_in[5];
  const float* wk   = (const float*)d_in[6];
  const float* wv   = (const float*)d_in[7];
  const float* bv   = (const float*)d_in[8];
  const float* wf   = (const float*)d_in[9];
  const float* bf   = (const float*)d_in[10];

  char* ws = (char*)d_ws;
  // workspace layout (bytes) -- ~44.7 MiB total (proven safe; 76.5 known bad).
  // d_out (16 MiB fp32, only read after gemm_out) doubles as scratch for
  // q_bf16 + k_bf16; wqt/wkt/wvt dead after gemm_qkv so attb aliases them.
  unsigned short* wft  = (unsigned short*)(ws + 0);          // 2 MiB, live till end
  unsigned short* wqt  = (unsigned short*)(ws + 2097152);    // 2 MiB
  unsigned short* wkt  = (unsigned short*)(ws + 4194304);    // 2 MiB
  unsigned short* wvt  = (unsigned short*)(ws + 6291456);    // 2 MiB
  unsigned short* attb = (unsigned short*)(ws + 2097152);    // 8 MiB alias
  unsigned short* qhp  = (unsigned short*)(ws + 10485760);   // 8 MiB
  unsigned short* khp  = (unsigned short*)(ws + 18874368);   // 8 MiB
  unsigned short* vtp  = (unsigned short*)(ws + 27262976);   // 8 MiB
  unsigned long long* mbits = (unsigned long long*)(ws + 35651584); // 1 MiB
  unsigned short* vb   = (unsigned short*)(ws + 36700160);   // 8 MiB
  unsigned short* qb   = (unsigned short*)d_out;             // 8 MiB (d_out scratch)
  unsigned short* kb   = (unsigned short*)d_out + 4194304;   // 8 MiB

  hipLaunchKernelGGL(cast3_kernel, dim3(2048, 3), dim3(256), 0, stream, q, k, v, qb, kb, vb);
  hipLaunchKernelGGL(wtrans_kernel, dim3(16, 16, 4), dim3(256), 0, stream,
                     wq, wk, wv, wf, wqt, wkt, wvt, wft);
  hipLaunchKernelGGL(maskpack_kernel, dim3(32768), dim3(256), 0, stream, mask, mbits);
  hipLaunchKernelGGL(gemm_qkv_kernel, dim3(768), dim3(256), 0, stream,
                     qb, kb, vb, wqt, wkt, wvt, bq, bv, qhp, khp, vtp);
  hipLaunchKernelGGL(attn_kernel, dim3(512), dim3(256), 0, stream,
                     qhp, khp, vtp, mbits, attb);
  hipLaunchKernelGGL(gemm_out_kernel, dim3(1024), dim3(256), 0, stream,
                     attb, wft, bf, (float*)d_out);
}

// Round 2
// 267.998 us; speedup vs baseline: 1.0772x; 1.0460x over previous
//
#include <hip/hip_runtime.h>

// ---- problem constants ----
#define D_MODEL 1024
#define NHEAD   16
#define DK      64
#define BATCH   2
#define SEQ     2048

typedef __attribute__((ext_vector_type(8))) short bf16x8;
typedef __attribute__((ext_vector_type(4))) short bf16x4;
typedef __attribute__((ext_vector_type(4))) float f32x4;
typedef __attribute__((ext_vector_type(2))) int i32x2;

#define QSCALE 0.18033688011f   // log2(e) / sqrt(64): folded into Q projection

__device__ __forceinline__ unsigned short f2b(float x) {
  unsigned u = __builtin_bit_cast(unsigned, x);
  u = (u + 0x7fffu + ((u >> 16) & 1u)) >> 16;   // RNE to bf16
  return (unsigned short)u;
}
// round-half-up bf16 (bias 2^-17 rel, error <= 2^-9 like RNE) -- 1 add
__device__ __forceinline__ unsigned short f2b_rhu(float x) {
  return (unsigned short)((__builtin_bit_cast(unsigned, x) + 0x8000u) >> 16);
}
// pack two fp32 -> two bf16 (round-half-up) in 3 VALU: add, add, v_perm
__device__ __forceinline__ int pk2(float a, float b) {
  unsigned ua = __builtin_bit_cast(unsigned, a) + 0x8000u;
  unsigned ub = __builtin_bit_cast(unsigned, b) + 0x8000u;
  return (int)__builtin_amdgcn_perm(ub, ua, 0x07060302u);  // [ub.hi16 : ua.hi16]
}
// same on raw (already-masked) fp32 bit patterns
__device__ __forceinline__ int pk2u(unsigned ua, unsigned ub) {
  return (int)__builtin_amdgcn_perm(ub + 0x8000u, ua + 0x8000u, 0x07060302u);
}

// async 16B global->LDS (m97 pattern). LDS dest = wave-uniform base + lane*16.
typedef const __attribute__((address_space(1))) void* gas_p;
typedef __attribute__((address_space(3))) void* las_p;
__device__ __forceinline__ void gll16(const void* g, void* l) {
  __builtin_amdgcn_global_load_lds((gas_p)g, (las_p)l, 16, 0, 0);
}

// 16x16x16 bf16 MFMA (K=16: A-frag k = quad*4+j, matching swapped-S C-layout)
__device__ __forceinline__ f32x4 mfma16(bf16x4 a, bf16x4 b, f32x4 c) {
#if __has_builtin(__builtin_amdgcn_mfma_f32_16x16x16bf16_1k)
  return __builtin_amdgcn_mfma_f32_16x16x16bf16_1k(a, b, c, 0, 0, 0);
#else
  f32x4 d;
  asm("v_mfma_f32_16x16x16_bf16 %0, %1, %2, %3" : "=v"(d) : "v"(a), "v"(b), "v"(c));
  return d;
#endif
}

// ---- fused preprocessing: cast3 + wtrans + maskpack in ONE launch ----
// blocks [0,6144): cast q/k/v fp32->bf16 (8 elems/thread)
// blocks [6144,7168): weight transpose+cast (64x64 tiles)
// blocks [7168,15360): mask bit-pack, 4 values/thread (4 ballots/wave)
__global__ __launch_bounds__(256) void prep_kernel(
    const float* __restrict__ q, const float* __restrict__ k, const float* __restrict__ v,
    unsigned short* __restrict__ qb, unsigned short* __restrict__ kb,
    unsigned short* __restrict__ vb,
    const float* __restrict__ wq, const float* __restrict__ wk,
    const float* __restrict__ wv, const float* __restrict__ wf,
    unsigned short* __restrict__ wqt, unsigned short* __restrict__ wkt,
    unsigned short* __restrict__ wvt, unsigned short* __restrict__ wft,
    const int* __restrict__ mask, unsigned long long* __restrict__ mbits) {
  int bid = blockIdx.x, t = threadIdx.x;
  if (bid < 6144) {
    int by = bid >> 11, bx = bid & 2047;
    const float* src = by == 0 ? q : (by == 1 ? k : v);
    unsigned short* dst = by == 0 ? qb : (by == 1 ? kb : vb);
    size_t i = ((size_t)bx * 256 + t) * 8;
    float4 x0 = *(const float4*)&src[i];
    float4 x1 = *(const float4*)&src[i + 4];
    int4 w;
    w.x = pk2(x0.x, x0.y); w.y = pk2(x0.z, x0.w);
    w.z = pk2(x1.x, x1.y); w.w = pk2(x1.z, x1.w);
    *(int4*)&dst[i] = w;
  } else if (bid < 7168) {
    __shared__ float tile[64][65];
    int idx = bid - 6144;
    int bz = idx >> 8, by = (idx >> 4) & 15, bx = idx & 15;
    const float* w; unsigned short* wt;
    switch (bz) {
      case 0: w = wq; wt = wqt; break;
      case 1: w = wk; wt = wkt; break;
      case 2: w = wv; wt = wvt; break;
      default: w = wf; wt = wft; break;
    }
    int r0 = by * 64, c0 = bx * 64;
    for (int i = 0; i < 16; ++i) {
      int idx2 = t + i * 256; int r = idx2 >> 6, c = idx2 & 63;
      tile[r][c] = w[(size_t)(r0 + r) * D_MODEL + c0 + c];
    }
    __syncthreads();
    for (int i = 0; i < 16; ++i) {
      int idx2 = t + i * 256; int r = idx2 >> 6, c = idx2 & 63;
      wt[(size_t)(c0 + r) * D_MODEL + r0 + c] = f2b(tile[c][r]);
    }
  } else {
    int idx = bid - 7168;             // [0, 8192)
    int lane = t & 63, wave = t >> 6;
    size_t base = ((size_t)idx * 4 + wave) * 256;   // 256 keys per wave
    unsigned long long b0 = __ballot(mask[base + lane] != 0);
    unsigned long long b1 = __ballot(mask[base + 64 + lane] != 0);
    unsigned long long b2 = __ballot(mask[base + 128 + lane] != 0);
    unsigned long long b3 = __ballot(mask[base + 192 + lane] != 0);
    if (lane == 0) {
      unsigned long long* p = &mbits[(size_t)idx * 16 + wave * 4];
      p[0] = b0; p[1] = b1; p[2] = b2; p[3] = b3;
    }
  }
}

// ---- fused QKV projection GEMM: 128x128 tile, BK=32, DOUBLE-BUFFERED
// async staging, ONE barrier per iteration (issue-early / drain-late).
// R11: q/k epilogue now LDS-staged -> fully-coalesced int4 stores (was 64
// scattered 2B stores/thread). ----
__global__ __launch_bounds__(256) void gemm_qkv_kernel(
    const unsigned short* __restrict__ qb, const unsigned short* __restrict__ kb,
    const unsigned short* __restrict__ vb,
    const unsigned short* __restrict__ wqt, const unsigned short* __restrict__ wkt,
    const unsigned short* __restrict__ wvt,
    const float* __restrict__ bq, const float* __restrict__ bv,
    unsigned short* __restrict__ qh, unsigned short* __restrict__ kh,
    unsigned short* __restrict__ vt) {
  // buffers: buf b at b*8192 (As at +0, Bs at +4096, each 128 rows x 32 cols);
  // epilogues alias the whole 16640-short region as SB[row][col] stride 130.
  __shared__ unsigned short SB[16640];
  int bid = blockIdx.x;
  int xcd = bid & 7, slot = bid >> 3;      // 96 slots per XCD
  int mi = slot & 3, zn = slot >> 2;       // 4 m-panels per XCD, zn in [0,24)
  int z = zn >> 3;
  int n0 = (zn & 7) * 128;
  int m0 = (mi * 8 + xcd) * 128;
  const unsigned short* A; const unsigned short* Bt;
  switch (z) {
    case 0:  A = qb; Bt = wqt; break;
    case 1:  A = kb; Bt = wkt; break;
    default: A = vb; Bt = wvt; break;
  }
  int t = threadIdx.x, lane = t & 63, wave = t >> 6;
  int l16 = lane & 15, quad = lane >> 4;
  int wm = (wave & 1) * 64, wn = (wave >> 1) * 64;
  f32x4 zero = {0.f, 0.f, 0.f, 0.f};
  f32x4 acc[4][4];
  for (int mt = 0; mt < 4; ++mt) for (int nt = 0; nt < 4; ++nt) acc[mt][nt] = zero;

  int drow = lane >> 2, dcol = (lane & 3) * 8;
  const unsigned short* asrc = A  + (size_t)(m0 + wave * 32 + drow) * D_MODEL + dcol;
  const unsigned short* bsrc = Bt + (size_t)(n0 + wave * 32 + drow) * D_MODEL + dcol;
  int dst = wave * 1024 + lane * 8;        // within-buffer wave slice (+g*512)

  // prologue: chunk 0 -> buf0
#pragma unroll
  for (int g = 0; g < 2; ++g) {
    gll16(asrc + (size_t)(g * 16) * D_MODEL, &SB[dst + g * 512]);
    gll16(bsrc + (size_t)(g * 16) * D_MODEL, &SB[4096 + dst + g * 512]);
  }
  for (int it = 0; it < 32; ++it) {
    __syncthreads();                       // drains chunk it's DMAs
    if (it + 1 < 32) {
      int nb = ((it + 1) & 1) * 8192, kn = (it + 1) * 32;
#pragma unroll
      for (int g = 0; g < 2; ++g) {
        gll16(asrc + (size_t)(g * 16) * D_MODEL + kn, &SB[nb + dst + g * 512]);
        gll16(bsrc + (size_t)(g * 16) * D_MODEL + kn, &SB[nb + 4096 + dst + g * 512]);
      }
    }
    int cb = (it & 1) * 8192;
    bf16x8 a[4], b[4];
    for (int mt = 0; mt < 4; ++mt)
      a[mt] = *(const bf16x8*)&SB[cb + (wm + mt * 16 + l16) * 32 + quad * 8];
    for (int nt = 0; nt < 4; ++nt)
      b[nt] = *(const bf16x8*)&SB[cb + 4096 + (wn + nt * 16 + l16) * 32 + quad * 8];
    for (int mt = 0; mt < 4; ++mt)
      for (int nt = 0; nt < 4; ++nt)
        acc[mt][nt] = __builtin_amdgcn_mfma_f32_16x16x32_bf16(a[mt], b[nt], acc[mt][nt], 0, 0, 0);
  }

  if (z == 2) {
    __syncthreads();
#pragma unroll
    for (int nt = 0; nt < 4; ++nt) {
      int col = wn + nt * 16 + l16;
      float bb = bv[n0 + col];
      for (int mt = 0; mt < 4; ++mt)
        for (int r = 0; r < 4; ++r)
          SB[col * 130 + wm + mt * 16 + quad * 4 + r] = f2b_rhu(acc[mt][nt][r] + bb);
    }
    __syncthreads();
    int c = t >> 1, hf = t & 1;
    int colg = n0 + c, hh = colg >> 6, dd = colg & 63;
    int b_ = m0 >> 11, sbase = m0 & (SEQ - 1);
    unsigned short* dstp = vt + (((size_t)(b_ * NHEAD + hh)) * DK + dd) * SEQ + sbase + hf * 64;
#pragma unroll
    for (int j = 0; j < 8; ++j)
      *(int4*)(dstp + j * 8) = *(const int4*)&SB[c * 130 + hf * 64 + j * 8];
  } else {
    // q/k epilogue: pack SB[s-row][col] (stride 130), then coalesced stores:
    // 8 lanes cover one 128B output row.
    __syncthreads();
#pragma unroll
    for (int nt = 0; nt < 4; ++nt) {
      int lcol = wn + nt * 16 + l16;
      float bb = (z == 0) ? bq[n0 + lcol] : 0.f;
      for (int mt = 0; mt < 4; ++mt)
        for (int r = 0; r < 4; ++r) {
          float val = acc[mt][nt][r] + bb;
          if (z == 0) val *= QSCALE;
          SB[(wm + mt * 16 + quad * 4 + r) * 130 + lcol] = f2b_rhu(val);
        }
    }
    __syncthreads();
    unsigned short* outp = (z == 0) ? qh : kh;
    int b_ = m0 >> 11, sbase = m0 & (SEQ - 1);
    int h0 = n0 >> 6, c = t & 7;
#pragma unroll
    for (int pass = 0; pass < 8; ++pass) {
      int rp = pass * 32 + (t >> 3);
      int srow = rp >> 1, part = rp & 1;
      unsigned short* dstp = outp +
          (((size_t)(b_ * NHEAD + h0 + part)) * SEQ + sbase + srow) * DK + c * 8;
      *(int4*)dstp = *(const int4*)&SB[srow * 130 + part * 64 + c * 8];
    }
  }
}

// ---- output projection GEMM: 64x64 tiles, BK=64 double-buffered,
// one barrier per iteration (same issue-early/drain-late scheme). ----
__global__ __launch_bounds__(256) void gemm_out_kernel(
    const unsigned short* __restrict__ A, const unsigned short* __restrict__ Bt,
    const float* __restrict__ bias, float* __restrict__ out) {
  __shared__ unsigned short As[8192], Bs[8192];   // buf b at b*4096, halves at +0,+2048
  int bid = blockIdx.x;
  int xcd = bid & 7, slot = bid >> 3;
  int mi = slot & 7, n0 = (slot >> 3) * 64;
  int m0 = (mi * 8 + xcd) * 64;
  int t = threadIdx.x, lane = t & 63, wave = t >> 6;
  int l16 = lane & 15, quad = lane >> 4;
  int wm = (wave & 1) * 32, wn = (wave >> 1) * 32;
  f32x4 zero = {0.f, 0.f, 0.f, 0.f};
  f32x4 acc[2][2];
  for (int mt = 0; mt < 2; ++mt) for (int nt = 0; nt < 2; ++nt) acc[mt][nt] = zero;

  int drow = lane >> 2, dcol = (lane & 3) * 8;
  const unsigned short* asrc = A  + (size_t)(m0 + wave * 16 + drow) * D_MODEL + dcol;
  const unsigned short* bsrc = Bt + (size_t)(n0 + wave * 16 + drow) * D_MODEL + dcol;
  int dst = wave * 512 + lane * 8;

#pragma unroll
  for (int hf = 0; hf < 2; ++hf) {
    gll16(asrc + hf * 32, &As[dst + hf * 2048]);
    gll16(bsrc + hf * 32, &Bs[dst + hf * 2048]);
  }
  for (int it = 0; it < 16; ++it) {
    __syncthreads();
    if (it + 1 < 16) {
      int nb = ((it + 1) & 1) * 4096, kn = (it + 1) * 64;
#pragma unroll
      for (int hf = 0; hf < 2; ++hf) {
        gll16(asrc + kn + hf * 32, &As[nb + dst + hf * 2048]);
        gll16(bsrc + kn + hf * 32, &Bs[nb + dst + hf * 2048]);
      }
    }
    int cb = (it & 1) * 4096;
#pragma unroll
    for (int half = 0; half < 2; ++half) {
      bf16x8 a[2], b[2];
      for (int mt = 0; mt < 2; ++mt)
        a[mt] = *(const bf16x8*)&As[cb + half * 2048 + (wm + mt * 16 + l16) * 32 + quad * 8];
      for (int nt = 0; nt < 2; ++nt)
        b[nt] = *(const bf16x8*)&Bs[cb + half * 2048 + (wn + nt * 16 + l16) * 32 + quad * 8];
      for (int mt = 0; mt < 2; ++mt)
        for (int nt = 0; nt < 2; ++nt)
          acc[mt][nt] = __builtin_amdgcn_mfma_f32_16x16x32_bf16(a[mt], b[nt], acc[mt][nt], 0, 0, 0);
    }
  }
  for (int nt = 0; nt < 2; ++nt) {
    int col = n0 + wn + nt * 16 + l16;
    float bb = bias[col];
    for (int mt = 0; mt < 2; ++mt)
      for (int r = 0; r < 4; ++r) {
        int row = m0 + wm + mt * 16 + quad * 4 + r;
        out[(size_t)row * D_MODEL + col] = acc[mt][nt][r] + bb;
      }
  }
}

// ---- flash attention, register-softmax (R10) + R11 restructure:
//  * 128-thread blocks (2 waves x 32 q-rows), grid 1024 -> FOUR independent
//    barrier domains per CU (LDS 4 x 32KB = 128KB). One block's exp2/pack
//    phase overlaps another's MFMA phase; barrier groups shrink 4->2 waves.
//  * mask words for tile tk loaded at iteration TOP (right after barrier) so
//    the S-MFMA phase hides their L2 latency (was a mid-iteration stall).
//  * K and V double-buffered, ONE barrier per kv-iter, issue-early/drain-late.
//  * LDS tiles [64][64] shorts with 16B-chunk XOR swizzle (chunk ^= row&7),
//    applied by pre-swizzling the gll16 global source; reads fold the XOR
//    into loop-invariant per-lane bases.
__global__ __launch_bounds__(128, 2) void attn_kernel(
    const unsigned short* __restrict__ qh, const unsigned short* __restrict__ kh,
    const unsigned short* __restrict__ vt, const unsigned long long* __restrict__ mbits,
    unsigned short* __restrict__ attb) {
  __shared__ unsigned short Ks[8192];   // 2 bufs x [64 k-rows][64 d], swizzled
  __shared__ unsigned short Vs[8192];   // 2 bufs x [64 d-rows][64 s], swizzled
  int bid = blockIdx.x;
  int xcd = bid & 7, slot = bid >> 3;   // 128 slots per XCD
  int bh_ = 4 * xcd + (slot >> 5);      // 4 bh per XCD (KV L2 locality)
  int qt = slot & 31;                   // 32 q-tiles of 64 rows
  int b = bh_ >> 4, h = bh_ & 15;
  int t = threadIdx.x, lane = t & 63, wave = t >> 6;
  int l16 = lane & 15, quad = lane >> 4;
  size_t bh = (size_t)b * NHEAD + h;

  const unsigned short* Kg = kh + bh * SEQ * DK;
  const unsigned short* Vg = vt + bh * DK * SEQ;
  const unsigned long long* mrow = mbits + (size_t)b * SEQ * (SEQ / 64);
  int qrowb = qt * 64 + wave * 32;

  // Q fragments straight from global (B-operand; row = q = l16, elems d)
  bf16x8 qf[2][2];
#pragma unroll
  for (int qm = 0; qm < 2; ++qm) {
    const unsigned short* Qg = qh + (bh * SEQ + (size_t)(qrowb + qm * 16 + l16)) * DK;
    qf[qm][0] = *(const bf16x8*)&Qg[quad * 8];
    qf[qm][1] = *(const bf16x8*)&Qg[32 + quad * 8];
  }

  // staging: 4 calls x (16 rows x 64 shorts); thread -> (row8 = t>>3, chunk = t&7)
  // global source chunk pre-swizzled: c = (t&7) ^ (row8&7).
  int srow8 = t >> 3;
  int schk = ((t & 7) ^ (srow8 & 7)) * 8;   // shorts
  const unsigned short* ksrc = Kg + (size_t)srow8 * DK + schk;
  const unsigned short* vsrc = Vg + (size_t)srow8 * SEQ + schk;
  int sdst = t * 8;                         // + g*1024 (shorts)

  // per-lane loop-invariant LDS read bases (XOR swizzle folded in)
  int x7 = l16 & 7;
  int ka0 = l16 * 64 + ((quad ^ x7) * 8);            // step 0: d-chunk = quad
  int ka1 = l16 * 64 + (((4 + quad) ^ x7) * 8);      // step 1: d-chunk = 4+quad
  int va[4];
#pragma unroll
  for (int nt = 0; nt < 4; ++nt)
    va[nt] = l16 * 64 + (((nt * 2 + (quad >> 1)) ^ x7) * 8) + (quad & 1) * 4;

  // mask index bases (one u64 per (q-row, kv-tile))
  size_t mi0 = (size_t)(qrowb + l16) * (SEQ / 64);
  size_t mi1 = (size_t)(qrowb + 16 + l16) * (SEQ / 64);

  bf16x4 ones4;
#pragma unroll
  for (int i = 0; i < 4; ++i) ones4[i] = (short)0x3F80;

  f32x4 zero = {0.f, 0.f, 0.f, 0.f};
  f32x4 accO[2][4], accRS[2];
#pragma unroll
  for (int qm = 0; qm < 2; ++qm) {
    accRS[qm] = zero;
    for (int dt = 0; dt < 4; ++dt) accO[qm][dt] = zero;
  }

  // prologue: K(0), V(0) -> buf0
#pragma unroll
  for (int g = 0; g < 4; ++g) {
    gll16(ksrc + (size_t)(g * 16) * DK, &Ks[g * 1024 + sdst]);
    gll16(vsrc + (size_t)(g * 16) * SEQ, &Vs[g * 1024 + sdst]);
  }

  for (int tk = 0; tk < SEQ / 64; ++tk) {
    __syncthreads();   // drains K(tk)+V(tk), issued a full compute phase ago
    if (tk + 1 < SEQ / 64) {
      int nb = ((tk + 1) & 1) * 4096;
      const unsigned short* kn = ksrc + (size_t)((tk + 1) * 64) * DK;
      const unsigned short* vn = vsrc + (tk + 1) * 64;
#pragma unroll
      for (int g = 0; g < 4; ++g) {
        gll16(kn + (size_t)(g * 16) * DK, &Ks[nb + g * 1024 + sdst]);
        gll16(vn + (size_t)(g * 16) * SEQ, &Vs[nb + g * 1024 + sdst]);
      }
    }
    // mask words issued EARLY; S-MFMA phase hides their latency
    unsigned long long mq0 = mrow[mi0 + tk];
    unsigned long long mq1 = mrow[mi1 + tk];

    int cb = (tk & 1) * 4096;

    // S^T = K . Q^T : lane's scores -> q = l16, k = nt*16 + quad*4 + r
    f32x4 accS[2][4];
#pragma unroll
    for (int qm = 0; qm < 2; ++qm)
      for (int nt = 0; nt < 4; ++nt) accS[qm][nt] = zero;
#pragma unroll
    for (int step = 0; step < 2; ++step) {
      int ka = step ? ka1 : ka0;
#pragma unroll
      for (int nt = 0; nt < 4; ++nt) {
        bf16x8 kf = *(const bf16x8*)&Ks[cb + ka + nt * 1024];
        accS[0][nt] = __builtin_amdgcn_mfma_f32_16x16x32_bf16(kf, qf[0][step], accS[0][nt], 0, 0, 0);
        accS[1][nt] = __builtin_amdgcn_mfma_f32_16x16x32_bf16(kf, qf[1][step], accS[1][nt], 0, 0, 0);
      }
    }

    // masked p = exp2(s), packed in-register into PV A-frags (k = quad*4 + j)
    bf16x4 ap[2][4];
#pragma unroll
    for (int qm = 0; qm < 2; ++qm) {
      unsigned long long mq = (qm ? mq1 : mq0) >> (quad * 4);
      unsigned mlo = (unsigned)mq, mhi = (unsigned)(mq >> 32);
#pragma unroll
      for (int nt = 0; nt < 4; ++nt) {
        unsigned w = (nt < 2) ? mlo : mhi;
        unsigned pu[4];
#pragma unroll
        for (int r = 0; r < 4; ++r) {
          float pv = __builtin_amdgcn_exp2f(accS[qm][nt][r]);
          int msk = ((int)(w << (31 - ((nt & 1) * 16 + r)))) >> 31;   // v_bfe_i32
          pu[r] = __builtin_bit_cast(unsigned, pv) & (unsigned)msk;
        }
        i32x2 wv;
        wv[0] = pk2u(pu[0], pu[1]);
        wv[1] = pk2u(pu[2], pu[3]);
        ap[qm][nt] = __builtin_bit_cast(bf16x4, wv);
      }
      // row sums on the MFMA pipe (accumulates in same layout as accO)
#pragma unroll
      for (int nt = 0; nt < 4; ++nt)
        accRS[qm] = mfma16(ap[qm][nt], ones4, accRS[qm]);
    }

    // O += P V  (V frags shared across both q-fragment sets)
#pragma unroll
    for (int nt = 0; nt < 4; ++nt) {
      int vb_ = cb + va[nt];
#pragma unroll
      for (int dt = 0; dt < 4; ++dt) {
        bf16x4 vf = *(const bf16x4*)&Vs[vb_ + dt * 1024];
        accO[0][dt] = mfma16(ap[0][nt], vf, accO[0][dt]);
        accO[1][dt] = mfma16(ap[1][nt], vf, accO[1][dt]);
      }
    }
  }

#pragma unroll
  for (int qm = 0; qm < 2; ++qm)
    for (int r = 0; r < 4; ++r) {
      float sden = accRS[qm][r];
      float inv = sden > 0.f ? 1.f / sden : 0.f;
      int row = qrowb + qm * 16 + quad * 4 + r;
      size_t ob = ((size_t)b * SEQ + row) * D_MODEL + (size_t)h * DK;
      for (int dt = 0; dt < 4; ++dt)
        attb[ob + dt * 16 + l16] = f2b_rhu(accO[qm][dt][r] * inv);
    }
}

extern "C" void kernel_launch(void* const* d_in, const int* in_sizes, int n_in,
                              void* d_out, int out_size, void* d_ws, size_t ws_size,
                              hipStream_t stream) {
  (void)in_sizes; (void)n_in; (void)out_size; (void)ws_size;
  const float* q    = (const float*)d_in[0];
  const float* k    = (const float*)d_in[1];
  const float* v    = (const float*)d_in[2];
  const int*   mask = (const int*)d_in[3];
  const float* wq   = (const float*)d_in[4];
  const float* bq   = (const float*)d_in[5];
  const float* wk   = (const float*)d_in[6];
  const float* wv   = (const float*)d_in[7];
  const float* bv   = (const float*)d_in[8];
  const float* wf   = (const float*)d_in[9];
  const float* bf   = (const float*)d_in[10];

  char* ws = (char*)d_ws;
  // workspace layout (bytes) -- ~44.7 MiB total (proven safe; 76.5 known bad).
  // d_out (16 MiB fp32, only read after gemm_out) doubles as scratch for
  // q_bf16 + k_bf16; wqt/wkt/wvt dead after gemm_qkv so attb aliases them.
  unsigned short* wft  = (unsigned short*)(ws + 0);          // 2 MiB, live till end
  unsigned short* wqt  = (unsigned short*)(ws + 2097152);    // 2 MiB
  unsigned short* wkt  = (unsigned short*)(ws + 4194304);    // 2 MiB
  unsigned short* wvt  = (unsigned short*)(ws + 6291456);    // 2 MiB
  unsigned short* attb = (unsigned short*)(ws + 2097152);    // 8 MiB alias
  unsigned short* qhp  = (unsigned short*)(ws + 10485760);   // 8 MiB
  unsigned short* khp  = (unsigned short*)(ws + 18874368);   // 8 MiB
  unsigned short* vtp  = (unsigned short*)(ws + 27262976);   // 8 MiB
  unsigned long long* mbits = (unsigned long long*)(ws + 35651584); // 1 MiB
  unsigned short* vb   = (unsigned short*)(ws + 36700160);   // 8 MiB
  unsigned short* qb   = (unsigned short*)d_out;             // 8 MiB (d_out scratch)
  unsigned short* kb   = (unsigned short*)d_out + 4194304;   // 8 MiB

  hipLaunchKernelGGL(prep_kernel, dim3(15360), dim3(256), 0, stream,
                     q, k, v, qb, kb, vb,
                     wq, wk, wv, wf, wqt, wkt, wvt, wft, mask, mbits);
  hipLaunchKernelGGL(gemm_qkv_kernel, dim3(768), dim3(256), 0, stream,
                     qb, kb, vb, wqt, wkt, wvt, bq, bv, qhp, khp, vtp);
  hipLaunchKernelGGL(attn_kernel, dim3(1024), dim3(128), 0, stream,
                     qhp, khp, vtp, mbits, attb);
  hipLaunchKernelGGL(gemm_out_kernel, dim3(1024), dim3(256), 0, stream,
                     attb, wft, bf, (float*)d_out);
}

// Round 4
// 261.666 us; speedup vs baseline: 1.1033x; 1.0242x over previous
//
#include <hip/hip_runtime.h>

// ---- problem constants ----
#define D_MODEL 1024
#define NHEAD   16
#define DK      64
#define BATCH   2
#define SEQ     2048

typedef __attribute__((ext_vector_type(8))) short bf16x8;
typedef __attribute__((ext_vector_type(4))) short bf16x4;
typedef __attribute__((ext_vector_type(4))) float f32x4;
typedef __attribute__((ext_vector_type(2))) int i32x2;

#define QSCALE 0.18033688011f   // log2(e) / sqrt(64): folded into Q projection

__device__ __forceinline__ unsigned short f2b(float x) {
  unsigned u = __builtin_bit_cast(unsigned, x);
  u = (u + 0x7fffu + ((u >> 16) & 1u)) >> 16;   // RNE to bf16
  return (unsigned short)u;
}
// round-half-up bf16 (bias 2^-17 rel, error <= 2^-9 like RNE) -- 1 add
__device__ __forceinline__ unsigned short f2b_rhu(float x) {
  return (unsigned short)((__builtin_bit_cast(unsigned, x) + 0x8000u) >> 16);
}
// pack two fp32 -> two bf16 (round-half-up) in 3 VALU: add, add, v_perm
__device__ __forceinline__ int pk2(float a, float b) {
  unsigned ua = __builtin_bit_cast(unsigned, a) + 0x8000u;
  unsigned ub = __builtin_bit_cast(unsigned, b) + 0x8000u;
  return (int)__builtin_amdgcn_perm(ub, ua, 0x07060302u);  // [ub.hi16 : ua.hi16]
}
// same on raw (already-masked) fp32 bit patterns (R2-proven)
__device__ __forceinline__ int pk2u(unsigned ua, unsigned ub) {
  return (int)__builtin_amdgcn_perm(ub + 0x8000u, ua + 0x8000u, 0x07060302u);
}

// async 16B global->LDS (m97 pattern). LDS dest = wave-uniform base + lane*16.
typedef const __attribute__((address_space(1))) void* gas_p;
typedef __attribute__((address_space(3))) void* las_p;
__device__ __forceinline__ void gll16(const void* g, void* l) {
  __builtin_amdgcn_global_load_lds((gas_p)g, (las_p)l, 16, 0, 0);
}

// 16x16x16 bf16 MFMA (K=16: A-frag k = quad*4+j, matching swapped-S C-layout)
__device__ __forceinline__ f32x4 mfma16(bf16x4 a, bf16x4 b, f32x4 c) {
#if __has_builtin(__builtin_amdgcn_mfma_f32_16x16x16bf16_1k)
  return __builtin_amdgcn_mfma_f32_16x16x16bf16_1k(a, b, c, 0, 0, 0);
#else
  f32x4 d;
  asm("v_mfma_f32_16x16x16_bf16 %0, %1, %2, %3" : "=v"(d) : "v"(a), "v"(b), "v"(c));
  return d;
#endif
}

// ---- fused preprocessing: cast3 + wtrans + maskpack in ONE launch ----
__global__ __launch_bounds__(256) void prep_kernel(
    const float* __restrict__ q, const float* __restrict__ k, const float* __restrict__ v,
    unsigned short* __restrict__ qb, unsigned short* __restrict__ kb,
    unsigned short* __restrict__ vb,
    const float* __restrict__ wq, const float* __restrict__ wk,
    const float* __restrict__ wv, const float* __restrict__ wf,
    unsigned short* __restrict__ wqt, unsigned short* __restrict__ wkt,
    unsigned short* __restrict__ wvt, unsigned short* __restrict__ wft,
    const int* __restrict__ mask, unsigned long long* __restrict__ mbits) {
  int bid = blockIdx.x, t = threadIdx.x;
  if (bid < 6144) {
    int by = bid >> 11, bx = bid & 2047;
    const float* src = by == 0 ? q : (by == 1 ? k : v);
    unsigned short* dst = by == 0 ? qb : (by == 1 ? kb : vb);
    size_t i = ((size_t)bx * 256 + t) * 8;
    float4 x0 = *(const float4*)&src[i];
    float4 x1 = *(const float4*)&src[i + 4];
    int4 w;
    w.x = pk2(x0.x, x0.y); w.y = pk2(x0.z, x0.w);
    w.z = pk2(x1.x, x1.y); w.w = pk2(x1.z, x1.w);
    *(int4*)&dst[i] = w;
  } else if (bid < 7168) {
    __shared__ float tile[64][65];
    int idx = bid - 6144;
    int bz = idx >> 8, by = (idx >> 4) & 15, bx = idx & 15;
    const float* w; unsigned short* wt;
    switch (bz) {
      case 0: w = wq; wt = wqt; break;
      case 1: w = wk; wt = wkt; break;
      case 2: w = wv; wt = wvt; break;
      default: w = wf; wt = wft; break;
    }
    int r0 = by * 64, c0 = bx * 64;
    for (int i = 0; i < 16; ++i) {
      int idx2 = t + i * 256; int r = idx2 >> 6, c = idx2 & 63;
      tile[r][c] = w[(size_t)(r0 + r) * D_MODEL + c0 + c];
    }
    __syncthreads();
    for (int i = 0; i < 16; ++i) {
      int idx2 = t + i * 256; int r = idx2 >> 6, c = idx2 & 63;
      wt[(size_t)(c0 + r) * D_MODEL + r0 + c] = f2b(tile[c][r]);
    }
  } else {
    int idx = bid - 7168;             // [0, 8192)
    int lane = t & 63, wave = t >> 6;
    size_t base = ((size_t)idx * 4 + wave) * 256;   // 256 keys per wave
    unsigned long long b0 = __ballot(mask[base + lane] != 0);
    unsigned long long b1 = __ballot(mask[base + 64 + lane] != 0);
    unsigned long long b2 = __ballot(mask[base + 128 + lane] != 0);
    unsigned long long b3 = __ballot(mask[base + 192 + lane] != 0);
    if (lane == 0) {
      unsigned long long* p = &mbits[(size_t)idx * 16 + wave * 4];
      p[0] = b0; p[1] = b1; p[2] = b2; p[3] = b3;
    }
  }
}

// ---- fused QKV projection GEMM: 128x128 tile, BK=32, double-buffered,
// one barrier per iteration; LDS-staged coalesced epilogues. ----
__global__ __launch_bounds__(256) void gemm_qkv_kernel(
    const unsigned short* __restrict__ qb, const unsigned short* __restrict__ kb,
    const unsigned short* __restrict__ vb,
    const unsigned short* __restrict__ wqt, const unsigned short* __restrict__ wkt,
    const unsigned short* __restrict__ wvt,
    const float* __restrict__ bq, const float* __restrict__ bv,
    unsigned short* __restrict__ qh, unsigned short* __restrict__ kh,
    unsigned short* __restrict__ vt) {
  __shared__ unsigned short SB[16640];
  int bid = blockIdx.x;
  int xcd = bid & 7, slot = bid >> 3;      // 96 slots per XCD
  int mi = slot & 3, zn = slot >> 2;       // 4 m-panels per XCD, zn in [0,24)
  int z = zn >> 3;
  int n0 = (zn & 7) * 128;
  int m0 = (mi * 8 + xcd) * 128;
  const unsigned short* A; const unsigned short* Bt;
  switch (z) {
    case 0:  A = qb; Bt = wqt; break;
    case 1:  A = kb; Bt = wkt; break;
    default: A = vb; Bt = wvt; break;
  }
  int t = threadIdx.x, lane = t & 63, wave = t >> 6;
  int l16 = lane & 15, quad = lane >> 4;
  int wm = (wave & 1) * 64, wn = (wave >> 1) * 64;
  f32x4 zero = {0.f, 0.f, 0.f, 0.f};
  f32x4 acc[4][4];
  for (int mt = 0; mt < 4; ++mt) for (int nt = 0; nt < 4; ++nt) acc[mt][nt] = zero;

  int drow = lane >> 2, dcol = (lane & 3) * 8;
  const unsigned short* asrc = A  + (size_t)(m0 + wave * 32 + drow) * D_MODEL + dcol;
  const unsigned short* bsrc = Bt + (size_t)(n0 + wave * 32 + drow) * D_MODEL + dcol;
  int dst = wave * 1024 + lane * 8;        // within-buffer wave slice (+g*512)

#pragma unroll
  for (int g = 0; g < 2; ++g) {
    gll16(asrc + (size_t)(g * 16) * D_MODEL, &SB[dst + g * 512]);
    gll16(bsrc + (size_t)(g * 16) * D_MODEL, &SB[4096 + dst + g * 512]);
  }
  for (int it = 0; it < 32; ++it) {
    __syncthreads();
    if (it + 1 < 32) {
      int nb = ((it + 1) & 1) * 8192, kn = (it + 1) * 32;
#pragma unroll
      for (int g = 0; g < 2; ++g) {
        gll16(asrc + (size_t)(g * 16) * D_MODEL + kn, &SB[nb + dst + g * 512]);
        gll16(bsrc + (size_t)(g * 16) * D_MODEL + kn, &SB[nb + 4096 + dst + g * 512]);
      }
    }
    int cb = (it & 1) * 8192;
    bf16x8 a[4], b[4];
    for (int mt = 0; mt < 4; ++mt)
      a[mt] = *(const bf16x8*)&SB[cb + (wm + mt * 16 + l16) * 32 + quad * 8];
    for (int nt = 0; nt < 4; ++nt)
      b[nt] = *(const bf16x8*)&SB[cb + 4096 + (wn + nt * 16 + l16) * 32 + quad * 8];
    for (int mt = 0; mt < 4; ++mt)
      for (int nt = 0; nt < 4; ++nt)
        acc[mt][nt] = __builtin_amdgcn_mfma_f32_16x16x32_bf16(a[mt], b[nt], acc[mt][nt], 0, 0, 0);
  }

  if (z == 2) {
    __syncthreads();
#pragma unroll
    for (int nt = 0; nt < 4; ++nt) {
      int col = wn + nt * 16 + l16;
      float bb = bv[n0 + col];
      for (int mt = 0; mt < 4; ++mt)
        for (int r = 0; r < 4; ++r)
          SB[col * 130 + wm + mt * 16 + quad * 4 + r] = f2b_rhu(acc[mt][nt][r] + bb);
    }
    __syncthreads();
    int c = t >> 1, hf = t & 1;
    int colg = n0 + c, hh = colg >> 6, dd = colg & 63;
    int b_ = m0 >> 11, sbase = m0 & (SEQ - 1);
    unsigned short* dstp = vt + (((size_t)(b_ * NHEAD + hh)) * DK + dd) * SEQ + sbase + hf * 64;
#pragma unroll
    for (int j = 0; j < 8; ++j)
      *(int4*)(dstp + j * 8) = *(const int4*)&SB[c * 130 + hf * 64 + j * 8];
  } else {
    __syncthreads();
#pragma unroll
    for (int nt = 0; nt < 4; ++nt) {
      int lcol = wn + nt * 16 + l16;
      float bb = (z == 0) ? bq[n0 + lcol] : 0.f;
      for (int mt = 0; mt < 4; ++mt)
        for (int r = 0; r < 4; ++r) {
          float val = acc[mt][nt][r] + bb;
          if (z == 0) val *= QSCALE;
          SB[(wm + mt * 16 + quad * 4 + r) * 130 + lcol] = f2b_rhu(val);
        }
    }
    __syncthreads();
    unsigned short* outp = (z == 0) ? qh : kh;
    int b_ = m0 >> 11, sbase = m0 & (SEQ - 1);
    int h0 = n0 >> 6, c = t & 7;
#pragma unroll
    for (int pass = 0; pass < 8; ++pass) {
      int rp = pass * 32 + (t >> 3);
      int srow = rp >> 1, part = rp & 1;
      unsigned short* dstp = outp +
          (((size_t)(b_ * NHEAD + h0 + part)) * SEQ + sbase + srow) * DK + c * 8;
      *(int4*)dstp = *(const int4*)&SB[srow * 130 + part * 64 + c * 8];
    }
  }
}

// ---- output projection GEMM: 64x64 tiles, BK=64 double-buffered ----
__global__ __launch_bounds__(256) void gemm_out_kernel(
    const unsigned short* __restrict__ A, const unsigned short* __restrict__ Bt,
    const float* __restrict__ bias, float* __restrict__ out) {
  __shared__ unsigned short As[8192], Bs[8192];
  int bid = blockIdx.x;
  int xcd = bid & 7, slot = bid >> 3;
  int mi = slot & 7, n0 = (slot >> 3) * 64;
  int m0 = (mi * 8 + xcd) * 64;
  int t = threadIdx.x, lane = t & 63, wave = t >> 6;
  int l16 = lane & 15, quad = lane >> 4;
  int wm = (wave & 1) * 32, wn = (wave >> 1) * 32;
  f32x4 zero = {0.f, 0.f, 0.f, 0.f};
  f32x4 acc[2][2];
  for (int mt = 0; mt < 2; ++mt) for (int nt = 0; nt < 2; ++nt) acc[mt][nt] = zero;

  int drow = lane >> 2, dcol = (lane & 3) * 8;
  const unsigned short* asrc = A  + (size_t)(m0 + wave * 16 + drow) * D_MODEL + dcol;
  const unsigned short* bsrc = Bt + (size_t)(n0 + wave * 16 + drow) * D_MODEL + dcol;
  int dst = wave * 512 + lane * 8;

#pragma unroll
  for (int hf = 0; hf < 2; ++hf) {
    gll16(asrc + hf * 32, &As[dst + hf * 2048]);
    gll16(bsrc + hf * 32, &Bs[dst + hf * 2048]);
  }
  for (int it = 0; it < 16; ++it) {
    __syncthreads();
    if (it + 1 < 16) {
      int nb = ((it + 1) & 1) * 4096, kn = (it + 1) * 64;
#pragma unroll
      for (int hf = 0; hf < 2; ++hf) {
        gll16(asrc + kn + hf * 32, &As[nb + dst + hf * 2048]);
        gll16(bsrc + kn + hf * 32, &Bs[nb + dst + hf * 2048]);
      }
    }
    int cb = (it & 1) * 4096;
#pragma unroll
    for (int half = 0; half < 2; ++half) {
      bf16x8 a[2], b[2];
      for (int mt = 0; mt < 2; ++mt)
        a[mt] = *(const bf16x8*)&As[cb + half * 2048 + (wm + mt * 16 + l16) * 32 + quad * 8];
      for (int nt = 0; nt < 2; ++nt)
        b[nt] = *(const bf16x8*)&Bs[cb + half * 2048 + (wn + nt * 16 + l16) * 32 + quad * 8];
      for (int mt = 0; mt < 2; ++mt)
        for (int nt = 0; nt < 2; ++nt)
          acc[mt][nt] = __builtin_amdgcn_mfma_f32_16x16x32_bf16(a[mt], b[nt], acc[mt][nt], 0, 0, 0);
    }
  }
  for (int nt = 0; nt < 2; ++nt) {
    int col = n0 + wn + nt * 16 + l16;
    float bb = bias[col];
    for (int mt = 0; mt < 2; ++mt)
      for (int r = 0; r < 4; ++r) {
        int row = m0 + wm + mt * 16 + quad * 4 + r;
        out[(size_t)row * D_MODEL + col] = acc[mt][nt][r] + bb;
      }
  }
}

// ---- flash attention, register-softmax, KVBLK=128 (R13):
// R12 structure (traced element-wise: staging swizzle and read swizzle are the
// same involution; all LDS accesses in-bounds) but with ONLY R2-proven softmax
// ops: explicit shift sign-mask + pk2u perm-pack + plain u64 mask loads.
// R12's untested sbfe builtin / v_cvt_pk asm are dropped (NaN suspects).
__global__ __launch_bounds__(256, 2) void attn_kernel(
    const unsigned short* __restrict__ qh, const unsigned short* __restrict__ kh,
    const unsigned short* __restrict__ vt, const unsigned long long* __restrict__ mbits,
    unsigned short* __restrict__ attb) {
  __shared__ unsigned short Ks[16384];  // 2 bufs x [128 k-rows][64 d], swizzled
  __shared__ unsigned short Vs[16384];  // 2 bufs x [64 d-rows][128 s], swizzled
  int bid = blockIdx.x;
  int xcd = bid & 7, slot = bid >> 3;   // 64 slots per XCD
  int bh_ = 4 * xcd + (slot >> 4);      // 4 bh per XCD (KV L2 locality)
  int qt = slot & 15;                   // 16 q-tiles of 128 rows
  int b = bh_ >> 4, h = bh_ & 15;
  int t = threadIdx.x, lane = t & 63, wave = t >> 6;
  int l16 = lane & 15, quad = lane >> 4;
  size_t bh = (size_t)b * NHEAD + h;

  const unsigned short* Kg = kh + bh * SEQ * DK;
  const unsigned short* Vg = vt + bh * DK * SEQ;
  const unsigned long long* mrow = mbits + (size_t)b * SEQ * (SEQ / 64);
  int qrowb = qt * 128 + wave * 32;

  // Q fragments straight from global (B-operand; row = q = l16, elems d)
  bf16x8 qf[2][2];
#pragma unroll
  for (int qm = 0; qm < 2; ++qm) {
    const unsigned short* Qg = qh + (bh * SEQ + (size_t)(qrowb + qm * 16 + l16)) * DK;
    qf[qm][0] = *(const bf16x8*)&Qg[quad * 8];
    qf[qm][1] = *(const bf16x8*)&Qg[32 + quad * 8];
  }

  // K staging: per gll16, 256 thr x 16B = 32 rows x 8 chunks. 4 calls/tile.
  int ksrow = t >> 3;
  int kschk = ((t & 7) ^ (ksrow & 7)) * 8;
  const unsigned short* ksrc = Kg + (size_t)ksrow * DK + kschk;
  // V staging: per gll16, 16 rows x 16 chunks. 4 calls/tile.
  int vsrow = t >> 4;
  int vschk = ((t & 15) ^ (vsrow & 15)) * 8;
  const unsigned short* vsrc = Vg + (size_t)vsrow * SEQ + vschk;
  int sdst = t * 8;                     // + g*2048 shorts per call

  // LDS read bases (XOR swizzle folded in, loop-invariant)
  int x7 = l16 & 7;
  int ka0 = l16 * 64 + ((quad ^ x7) * 8);            // K: step 0, + nt*1024
  int ka1 = l16 * 64 + (((4 + quad) ^ x7) * 8);      // K: step 1
  int va[2][4];
#pragma unroll
  for (int sub = 0; sub < 2; ++sub)
#pragma unroll
    for (int nt = 0; nt < 4; ++nt)
      va[sub][nt] = l16 * 128 + (((sub * 8 + nt * 2 + (quad >> 1)) ^ l16) * 8)
                    + (quad & 1) * 4;                // V: + dt*2048

  // mask index bases (one u64 per (q-row, 64-key tile))
  size_t mi0 = (size_t)(qrowb + l16) * (SEQ / 64);
  size_t mi1 = (size_t)(qrowb + 16 + l16) * (SEQ / 64);

  bf16x4 ones4;
#pragma unroll
  for (int i = 0; i < 4; ++i) ones4[i] = (short)0x3F80;

  f32x4 zero = {0.f, 0.f, 0.f, 0.f};
  f32x4 accO[2][4], accRS[2];
#pragma unroll
  for (int qm = 0; qm < 2; ++qm) {
    accRS[qm] = zero;
    for (int dt = 0; dt < 4; ++dt) accO[qm][dt] = zero;
  }

  // prologue: K(0), V(0) -> buf0
#pragma unroll
  for (int g = 0; g < 4; ++g) {
    gll16(ksrc + (size_t)(g * 32) * DK, &Ks[g * 2048 + sdst]);
    gll16(vsrc + (size_t)(g * 16) * SEQ, &Vs[g * 2048 + sdst]);
  }

  for (int tk = 0; tk < SEQ / 128; ++tk) {
    __syncthreads();   // drains K(tk)+V(tk), issued a full compute phase ago
    if (tk + 1 < SEQ / 128) {
      int nb = ((tk + 1) & 1) * 8192;
      const unsigned short* kn = ksrc + (size_t)(tk + 1) * 128 * DK;
      const unsigned short* vn = vsrc + (tk + 1) * 128;
#pragma unroll
      for (int g = 0; g < 4; ++g) {
        gll16(kn + (size_t)(g * 32) * DK, &Ks[nb + g * 2048 + sdst]);
        gll16(vn + (size_t)(g * 16) * SEQ, &Vs[nb + g * 2048 + sdst]);
      }
    }
    // both sub-tiles' mask words, issued early (S-MFMA hides the latency)
    unsigned long long mA0 = mrow[mi0 + 2 * tk];
    unsigned long long mA1 = mrow[mi0 + 2 * tk + 1];
    unsigned long long mB0 = mrow[mi1 + 2 * tk];
    unsigned long long mB1 = mrow[mi1 + 2 * tk + 1];

    int cb = (tk & 1) * 8192;
#pragma unroll
    for (int sub = 0; sub < 2; ++sub) {
      int kb_ = cb + sub * 4096;
      // S^T = K . Q^T : lane's scores -> q = l16, k = nt*16 + quad*4 + r
      f32x4 accS[2][4];
#pragma unroll
      for (int qm = 0; qm < 2; ++qm)
        for (int nt = 0; nt < 4; ++nt) accS[qm][nt] = zero;
#pragma unroll
      for (int step = 0; step < 2; ++step) {
        int ka = step ? ka1 : ka0;
#pragma unroll
        for (int nt = 0; nt < 4; ++nt) {
          bf16x8 kf = *(const bf16x8*)&Ks[kb_ + ka + nt * 1024];
          accS[0][nt] = __builtin_amdgcn_mfma_f32_16x16x32_bf16(kf, qf[0][step], accS[0][nt], 0, 0, 0);
          accS[1][nt] = __builtin_amdgcn_mfma_f32_16x16x32_bf16(kf, qf[1][step], accS[1][nt], 0, 0, 0);
        }
      }

      // masked p = exp2(s), packed in-register into PV A-frags (k = quad*4+j)
      // (R2-proven ops: shift sign-mask + pk2u)
      unsigned long long ms0 = sub ? mA1 : mA0;
      unsigned long long ms1 = sub ? mB1 : mB0;
      bf16x4 ap[2][4];
#pragma unroll
      for (int qm = 0; qm < 2; ++qm) {
        unsigned long long mq = (qm ? ms1 : ms0) >> (quad * 4);
        unsigned mlo = (unsigned)mq, mhi = (unsigned)(mq >> 32);
#pragma unroll
        for (int nt = 0; nt < 4; ++nt) {
          unsigned w = (nt < 2) ? mlo : mhi;
          unsigned pu[4];
#pragma unroll
          for (int r = 0; r < 4; ++r) {
            float pv = __builtin_amdgcn_exp2f(accS[qm][nt][r]);
            int msk = ((int)(w << (31 - ((nt & 1) * 16 + r)))) >> 31;
            pu[r] = __builtin_bit_cast(unsigned, pv) & (unsigned)msk;
          }
          i32x2 wv;
          wv[0] = pk2u(pu[0], pu[1]);
          wv[1] = pk2u(pu[2], pu[3]);
          ap[qm][nt] = __builtin_bit_cast(bf16x4, wv);
        }
        // row sums on the MFMA pipe (same layout as accO)
#pragma unroll
        for (int nt = 0; nt < 4; ++nt)
          accRS[qm] = mfma16(ap[qm][nt], ones4, accRS[qm]);
      }

      // O += P V  (V frags shared across both q-fragment sets)
#pragma unroll
      for (int nt = 0; nt < 4; ++nt) {
        int vb_ = cb + va[sub][nt];
#pragma unroll
        for (int dt = 0; dt < 4; ++dt) {
          bf16x4 vf = *(const bf16x4*)&Vs[vb_ + dt * 2048];
          accO[0][dt] = mfma16(ap[0][nt], vf, accO[0][dt]);
          accO[1][dt] = mfma16(ap[1][nt], vf, accO[1][dt]);
        }
      }
    }
  }

#pragma unroll
  for (int qm = 0; qm < 2; ++qm)
    for (int r = 0; r < 4; ++r) {
      float sden = accRS[qm][r];
      float inv = sden > 0.f ? 1.f / sden : 0.f;
      int row = qrowb + qm * 16 + quad * 4 + r;
      size_t ob = ((size_t)b * SEQ + row) * D_MODEL + (size_t)h * DK;
      for (int dt = 0; dt < 4; ++dt)
        attb[ob + dt * 16 + l16] = f2b_rhu(accO[qm][dt][r] * inv);
    }
}

extern "C" void kernel_launch(void* const* d_in, const int* in_sizes, int n_in,
                              void* d_out, int out_size, void* d_ws, size_t ws_size,
                              hipStream_t stream) {
  (void)in_sizes; (void)n_in; (void)out_size; (void)ws_size;
  const float* q    = (const float*)d_in[0];
  const float* k    = (const float*)d_in[1];
  const float* v    = (const float*)d_in[2];
  const int*   mask = (const int*)d_in[3];
  const float* wq   = (const float*)d_in[4];
  const float* bq   = (const float*)d_in[5];
  const float* wk   = (const float*)d_in[6];
  const float* wv   = (const float*)d_in[7];
  const float* bv   = (const float*)d_in[8];
  const float* wf   = (const float*)d_in[9];
  const float* bf   = (const float*)d_in[10];

  char* ws = (char*)d_ws;
  unsigned short* wft  = (unsigned short*)(ws + 0);          // 2 MiB, live till end
  unsigned short* wqt  = (unsigned short*)(ws + 2097152);    // 2 MiB
  unsigned short* wkt  = (unsigned short*)(ws + 4194304);    // 2 MiB
  unsigned short* wvt  = (unsigned short*)(ws + 6291456);    // 2 MiB
  unsigned short* attb = (unsigned short*)(ws + 2097152);    // 8 MiB alias
  unsigned short* qhp  = (unsigned short*)(ws + 10485760);   // 8 MiB
  unsigned short* khp  = (unsigned short*)(ws + 18874368);   // 8 MiB
  unsigned short* vtp  = (unsigned short*)(ws + 27262976);   // 8 MiB
  unsigned long long* mbits = (unsigned long long*)(ws + 35651584); // 1 MiB
  unsigned short* vb   = (unsigned short*)(ws + 36700160);   // 8 MiB
  unsigned short* qb   = (unsigned short*)d_out;             // 8 MiB (d_out scratch)
  unsigned short* kb   = (unsigned short*)d_out + 4194304;   // 8 MiB

  hipLaunchKernelGGL(prep_kernel, dim3(15360), dim3(256), 0, stream,
                     q, k, v, qb, kb, vb,
                     wq, wk, wv, wf, wqt, wkt, wvt, wft, mask, mbits);
  hipLaunchKernelGGL(gemm_qkv_kernel, dim3(768), dim3(256), 0, stream,
                     qb, kb, vb, wqt, wkt, wvt, bq, bv, qhp, khp, vtp);
  hipLaunchKernelGGL(attn_kernel, dim3(512), dim3(256), 0, stream,
                     qhp, khp, vtp, mbits, attb);
  hipLaunchKernelGGL(gemm_out_kernel, dim3(1024), dim3(256), 0, stream,
                     attb, wft, bf, (float*)d_out);
}

// Round 5
// 250.143 us; speedup vs baseline: 1.1541x; 1.0461x over previous
//
#include <hip/hip_runtime.h>

// ---- problem constants ----
#define D_MODEL 1024
#define NHEAD   16
#define DK      64
#define BATCH   2
#define SEQ     2048

typedef __attribute__((ext_vector_type(8))) short bf16x8;
typedef __attribute__((ext_vector_type(4))) short bf16x4;
typedef __attribute__((ext_vector_type(4))) float f32x4;
typedef __attribute__((ext_vector_type(2))) int i32x2;

#define QSCALE 0.18033688011f   // log2(e) / sqrt(64): folded into Q projection

__device__ __forceinline__ unsigned short f2b(float x) {
  unsigned u = __builtin_bit_cast(unsigned, x);
  u = (u + 0x7fffu + ((u >> 16) & 1u)) >> 16;   // RNE to bf16
  return (unsigned short)u;
}
// round-half-up bf16 (bias 2^-17 rel, error <= 2^-9 like RNE) -- 1 add
__device__ __forceinline__ unsigned short f2b_rhu(float x) {
  return (unsigned short)((__builtin_bit_cast(unsigned, x) + 0x8000u) >> 16);
}
// pack two fp32 -> two bf16 (round-half-up) in 3 VALU: add, add, v_perm
__device__ __forceinline__ int pk2(float a, float b) {
  unsigned ua = __builtin_bit_cast(unsigned, a) + 0x8000u;
  unsigned ub = __builtin_bit_cast(unsigned, b) + 0x8000u;
  return (int)__builtin_amdgcn_perm(ub, ua, 0x07060302u);  // [ub.hi16 : ua.hi16]
}
// same on raw (already-masked) fp32 bit patterns (R2-proven)
__device__ __forceinline__ int pk2u(unsigned ua, unsigned ub) {
  return (int)__builtin_amdgcn_perm(ub + 0x8000u, ua + 0x8000u, 0x07060302u);
}

// async 16B global->LDS (m97 pattern). LDS dest = wave-uniform base + lane*16.
typedef const __attribute__((address_space(1))) void* gas_p;
typedef __attribute__((address_space(3))) void* las_p;
__device__ __forceinline__ void gll16(const void* g, void* l) {
  __builtin_amdgcn_global_load_lds((gas_p)g, (las_p)l, 16, 0, 0);
}

// 16x16x16 bf16 MFMA (K=16: A-frag k = quad*4+j, matching swapped-S C-layout)
__device__ __forceinline__ f32x4 mfma16(bf16x4 a, bf16x4 b, f32x4 c) {
#if __has_builtin(__builtin_amdgcn_mfma_f32_16x16x16bf16_1k)
  return __builtin_amdgcn_mfma_f32_16x16x16bf16_1k(a, b, c, 0, 0, 0);
#else
  f32x4 d;
  asm("v_mfma_f32_16x16x16_bf16 %0, %1, %2, %3" : "=v"(d) : "v"(a), "v"(b), "v"(c));
  return d;
#endif
}

// ---- fused preprocessing: cast3 + wtrans + maskpack in ONE launch ----
__global__ __launch_bounds__(256) void prep_kernel(
    const float* __restrict__ q, const float* __restrict__ k, const float* __restrict__ v,
    unsigned short* __restrict__ qb, unsigned short* __restrict__ kb,
    unsigned short* __restrict__ vb,
    const float* __restrict__ wq, const float* __restrict__ wk,
    const float* __restrict__ wv, const float* __restrict__ wf,
    unsigned short* __restrict__ wqt, unsigned short* __restrict__ wkt,
    unsigned short* __restrict__ wvt, unsigned short* __restrict__ wft,
    const int* __restrict__ mask, unsigned long long* __restrict__ mbits) {
  int bid = blockIdx.x, t = threadIdx.x;
  if (bid < 6144) {
    int by = bid >> 11, bx = bid & 2047;
    const float* src = by == 0 ? q : (by == 1 ? k : v);
    unsigned short* dst = by == 0 ? qb : (by == 1 ? kb : vb);
    size_t i = ((size_t)bx * 256 + t) * 8;
    float4 x0 = *(const float4*)&src[i];
    float4 x1 = *(const float4*)&src[i + 4];
    int4 w;
    w.x = pk2(x0.x, x0.y); w.y = pk2(x0.z, x0.w);
    w.z = pk2(x1.x, x1.y); w.w = pk2(x1.z, x1.w);
    *(int4*)&dst[i] = w;
  } else if (bid < 7168) {
    __shared__ float tile[64][65];
    int idx = bid - 6144;
    int bz = idx >> 8, by = (idx >> 4) & 15, bx = idx & 15;
    const float* w; unsigned short* wt;
    switch (bz) {
      case 0: w = wq; wt = wqt; break;
      case 1: w = wk; wt = wkt; break;
      case 2: w = wv; wt = wvt; break;
      default: w = wf; wt = wft; break;
    }
    int r0 = by * 64, c0 = bx * 64;
    for (int i = 0; i < 16; ++i) {
      int idx2 = t + i * 256; int r = idx2 >> 6, c = idx2 & 63;
      tile[r][c] = w[(size_t)(r0 + r) * D_MODEL + c0 + c];
    }
    __syncthreads();
    for (int i = 0; i < 16; ++i) {
      int idx2 = t + i * 256; int r = idx2 >> 6, c = idx2 & 63;
      wt[(size_t)(c0 + r) * D_MODEL + r0 + c] = f2b(tile[c][r]);
    }
  } else {
    int idx = bid - 7168;             // [0, 8192)
    int lane = t & 63, wave = t >> 6;
    size_t base = ((size_t)idx * 4 + wave) * 256;   // 256 keys per wave
    unsigned long long b0 = __ballot(mask[base + lane] != 0);
    unsigned long long b1 = __ballot(mask[base + 64 + lane] != 0);
    unsigned long long b2 = __ballot(mask[base + 128 + lane] != 0);
    unsigned long long b3 = __ballot(mask[base + 192 + lane] != 0);
    if (lane == 0) {
      unsigned long long* p = &mbits[(size_t)idx * 16 + wave * 4];
      p[0] = b0; p[1] = b1; p[2] = b2; p[3] = b3;
    }
  }
}

// ---- fused QKV projection GEMM: 128x128 tile, BK=32, double-buffered,
// one barrier per iteration; LDS-staged coalesced epilogues. ----
__global__ __launch_bounds__(256) void gemm_qkv_kernel(
    const unsigned short* __restrict__ qb, const unsigned short* __restrict__ kb,
    const unsigned short* __restrict__ vb,
    const unsigned short* __restrict__ wqt, const unsigned short* __restrict__ wkt,
    const unsigned short* __restrict__ wvt,
    const float* __restrict__ bq, const float* __restrict__ bv,
    unsigned short* __restrict__ qh, unsigned short* __restrict__ kh,
    unsigned short* __restrict__ vt) {
  __shared__ unsigned short SB[16640];
  int bid = blockIdx.x;
  int xcd = bid & 7, slot = bid >> 3;      // 96 slots per XCD
  int mi = slot & 3, zn = slot >> 2;       // 4 m-panels per XCD, zn in [0,24)
  int z = zn >> 3;
  int n0 = (zn & 7) * 128;
  int m0 = (mi * 8 + xcd) * 128;
  const unsigned short* A; const unsigned short* Bt;
  switch (z) {
    case 0:  A = qb; Bt = wqt; break;
    case 1:  A = kb; Bt = wkt; break;
    default: A = vb; Bt = wvt; break;
  }
  int t = threadIdx.x, lane = t & 63, wave = t >> 6;
  int l16 = lane & 15, quad = lane >> 4;
  int wm = (wave & 1) * 64, wn = (wave >> 1) * 64;
  f32x4 zero = {0.f, 0.f, 0.f, 0.f};
  f32x4 acc[4][4];
  for (int mt = 0; mt < 4; ++mt) for (int nt = 0; nt < 4; ++nt) acc[mt][nt] = zero;

  int drow = lane >> 2, dcol = (lane & 3) * 8;
  const unsigned short* asrc = A  + (size_t)(m0 + wave * 32 + drow) * D_MODEL + dcol;
  const unsigned short* bsrc = Bt + (size_t)(n0 + wave * 32 + drow) * D_MODEL + dcol;
  int dst = wave * 1024 + lane * 8;        // within-buffer wave slice (+g*512)

#pragma unroll
  for (int g = 0; g < 2; ++g) {
    gll16(asrc + (size_t)(g * 16) * D_MODEL, &SB[dst + g * 512]);
    gll16(bsrc + (size_t)(g * 16) * D_MODEL, &SB[4096 + dst + g * 512]);
  }
  for (int it = 0; it < 32; ++it) {
    __syncthreads();
    if (it + 1 < 32) {
      int nb = ((it + 1) & 1) * 8192, kn = (it + 1) * 32;
#pragma unroll
      for (int g = 0; g < 2; ++g) {
        gll16(asrc + (size_t)(g * 16) * D_MODEL + kn, &SB[nb + dst + g * 512]);
        gll16(bsrc + (size_t)(g * 16) * D_MODEL + kn, &SB[nb + 4096 + dst + g * 512]);
      }
    }
    int cb = (it & 1) * 8192;
    bf16x8 a[4], b[4];
    for (int mt = 0; mt < 4; ++mt)
      a[mt] = *(const bf16x8*)&SB[cb + (wm + mt * 16 + l16) * 32 + quad * 8];
    for (int nt = 0; nt < 4; ++nt)
      b[nt] = *(const bf16x8*)&SB[cb + 4096 + (wn + nt * 16 + l16) * 32 + quad * 8];
    for (int mt = 0; mt < 4; ++mt)
      for (int nt = 0; nt < 4; ++nt)
        acc[mt][nt] = __builtin_amdgcn_mfma_f32_16x16x32_bf16(a[mt], b[nt], acc[mt][nt], 0, 0, 0);
  }

  if (z == 2) {
    __syncthreads();
#pragma unroll
    for (int nt = 0; nt < 4; ++nt) {
      int col = wn + nt * 16 + l16;
      float bb = bv[n0 + col];
      for (int mt = 0; mt < 4; ++mt)
        for (int r = 0; r < 4; ++r)
          SB[col * 130 + wm + mt * 16 + quad * 4 + r] = f2b_rhu(acc[mt][nt][r] + bb);
    }
    __syncthreads();
    int c = t >> 1, hf = t & 1;
    int colg = n0 + c, hh = colg >> 6, dd = colg & 63;
    int b_ = m0 >> 11, sbase = m0 & (SEQ - 1);
    unsigned short* dstp = vt + (((size_t)(b_ * NHEAD + hh)) * DK + dd) * SEQ + sbase + hf * 64;
#pragma unroll
    for (int j = 0; j < 8; ++j)
      *(int4*)(dstp + j * 8) = *(const int4*)&SB[c * 130 + hf * 64 + j * 8];
  } else {
    __syncthreads();
#pragma unroll
    for (int nt = 0; nt < 4; ++nt) {
      int lcol = wn + nt * 16 + l16;
      float bb = (z == 0) ? bq[n0 + lcol] : 0.f;
      for (int mt = 0; mt < 4; ++mt)
        for (int r = 0; r < 4; ++r) {
          float val = acc[mt][nt][r] + bb;
          if (z == 0) val *= QSCALE;
          SB[(wm + mt * 16 + quad * 4 + r) * 130 + lcol] = f2b_rhu(val);
        }
    }
    __syncthreads();
    unsigned short* outp = (z == 0) ? qh : kh;
    int b_ = m0 >> 11, sbase = m0 & (SEQ - 1);
    int h0 = n0 >> 6, c = t & 7;
#pragma unroll
    for (int pass = 0; pass < 8; ++pass) {
      int rp = pass * 32 + (t >> 3);
      int srow = rp >> 1, part = rp & 1;
      unsigned short* dstp = outp +
          (((size_t)(b_ * NHEAD + h0 + part)) * SEQ + sbase + srow) * DK + c * 8;
      *(int4*)dstp = *(const int4*)&SB[srow * 130 + part * 64 + c * 8];
    }
  }
}

// ---- output projection GEMM: 64x64 tiles, BK=64 double-buffered ----
__global__ __launch_bounds__(256) void gemm_out_kernel(
    const unsigned short* __restrict__ A, const unsigned short* __restrict__ Bt,
    const float* __restrict__ bias, float* __restrict__ out) {
  __shared__ unsigned short As[8192], Bs[8192];
  int bid = blockIdx.x;
  int xcd = bid & 7, slot = bid >> 3;
  int mi = slot & 7, n0 = (slot >> 3) * 64;
  int m0 = (mi * 8 + xcd) * 64;
  int t = threadIdx.x, lane = t & 63, wave = t >> 6;
  int l16 = lane & 15, quad = lane >> 4;
  int wm = (wave & 1) * 32, wn = (wave >> 1) * 32;
  f32x4 zero = {0.f, 0.f, 0.f, 0.f};
  f32x4 acc[2][2];
  for (int mt = 0; mt < 2; ++mt) for (int nt = 0; nt < 2; ++nt) acc[mt][nt] = zero;

  int drow = lane >> 2, dcol = (lane & 3) * 8;
  const unsigned short* asrc = A  + (size_t)(m0 + wave * 16 + drow) * D_MODEL + dcol;
  const unsigned short* bsrc = Bt + (size_t)(n0 + wave * 16 + drow) * D_MODEL + dcol;
  int dst = wave * 512 + lane * 8;

#pragma unroll
  for (int hf = 0; hf < 2; ++hf) {
    gll16(asrc + hf * 32, &As[dst + hf * 2048]);
    gll16(bsrc + hf * 32, &Bs[dst + hf * 2048]);
  }
  for (int it = 0; it < 16; ++it) {
    __syncthreads();
    if (it + 1 < 16) {
      int nb = ((it + 1) & 1) * 4096, kn = (it + 1) * 64;
#pragma unroll
      for (int hf = 0; hf < 2; ++hf) {
        gll16(asrc + kn + hf * 32, &As[nb + dst + hf * 2048]);
        gll16(bsrc + kn + hf * 32, &Bs[nb + dst + hf * 2048]);
      }
    }
    int cb = (it & 1) * 4096;
#pragma unroll
    for (int half = 0; half < 2; ++half) {
      bf16x8 a[2], b[2];
      for (int mt = 0; mt < 2; ++mt)
        a[mt] = *(const bf16x8*)&As[cb + half * 2048 + (wm + mt * 16 + l16) * 32 + quad * 8];
      for (int nt = 0; nt < 2; ++nt)
        b[nt] = *(const bf16x8*)&Bs[cb + half * 2048 + (wn + nt * 16 + l16) * 32 + quad * 8];
      for (int mt = 0; mt < 2; ++mt)
        for (int nt = 0; nt < 2; ++nt)
          acc[mt][nt] = __builtin_amdgcn_mfma_f32_16x16x32_bf16(a[mt], b[nt], acc[mt][nt], 0, 0, 0);
    }
  }
  for (int nt = 0; nt < 2; ++nt) {
    int col = n0 + wn + nt * 16 + l16;
    float bb = bias[col];
    for (int mt = 0; mt < 2; ++mt)
      for (int r = 0; r < 4; ++r) {
        int row = m0 + wm + mt * 16 + quad * 4 + r;
        out[(size_t)row * D_MODEL + col] = acc[mt][nt][r] + bb;
      }
  }
}

// ---- flash attention R14: 8-wave blocks, 16 q-rows/wave ----
// Same 128-row q-tiles / 512 grid / KVBLK=128 / 64KB LDS as R13, but blocks
// are 8 waves x 16 rows (was 4 x 32): 16 waves/CU = 4/SIMD (was 2/SIMD),
// doubling latency hiding of the K-dsread->MFMA->softmax->PV chain. Staging
// per q-row UNCHANGED (the R2 trap). Cost: K-frag LDS reads no longer shared
// across 2 qm -> LDS-read cycles/CU double (~6.1k/iter, within the new wall).
// Bank math: bank = 4*chunk (row drops out of bank index); XOR spread gives
// 2-way aliasing on b128 = free (m136). Plus T5 setprio around MFMA clusters
// (attn-positive, m191; 2 indie blocks/CU + 8 drifting waves to arbitrate).
__global__ __launch_bounds__(512, 4) void attn_kernel(
    const unsigned short* __restrict__ qh, const unsigned short* __restrict__ kh,
    const unsigned short* __restrict__ vt, const unsigned long long* __restrict__ mbits,
    unsigned short* __restrict__ attb) {
  __shared__ unsigned short Ks[16384];  // 2 bufs x [128 k-rows][64 d], swizzled
  __shared__ unsigned short Vs[16384];  // 2 bufs x [64 d-rows][128 s], swizzled
  int bid = blockIdx.x;
  int xcd = bid & 7, slot = bid >> 3;   // 64 slots per XCD
  int bh_ = 4 * xcd + (slot >> 4);      // 4 bh per XCD (KV L2 locality)
  int qt = slot & 15;                   // 16 q-tiles of 128 rows
  int b = bh_ >> 4, h = bh_ & 15;
  int t = threadIdx.x, lane = t & 63, wave = t >> 6;   // wave in [0,8)
  int l16 = lane & 15, quad = lane >> 4;
  size_t bh = (size_t)b * NHEAD + h;

  const unsigned short* Kg = kh + bh * SEQ * DK;
  const unsigned short* Vg = vt + bh * DK * SEQ;
  const unsigned long long* mrow = mbits + (size_t)b * SEQ * (SEQ / 64);
  int qrowb = qt * 128 + wave * 16;     // this wave's 16 q-rows

  // Q fragments straight from global (B-operand; row = q = l16, elems d)
  bf16x8 qf[2];
  {
    const unsigned short* Qg = qh + (bh * SEQ + (size_t)(qrowb + l16)) * DK;
    qf[0] = *(const bf16x8*)&Qg[quad * 8];
    qf[1] = *(const bf16x8*)&Qg[32 + quad * 8];
  }

  // K staging: per gll16, 512 thr x 16B = 64 rows x 8 chunks. 2 calls/tile.
  int ksrow = t >> 3;                       // [0,64)
  int kschk = ((t & 7) ^ (ksrow & 7)) * 8;
  const unsigned short* ksrc = Kg + (size_t)ksrow * DK + kschk;
  // V staging: per gll16, 32 rows x 16 chunks. 2 calls/tile.
  int vsrow = t >> 4;                       // [0,32)
  int vschk = ((t & 15) ^ (vsrow & 15)) * 8;
  const unsigned short* vsrc = Vg + (size_t)vsrow * SEQ + vschk;
  int sdst = t * 8;                         // + g*4096 shorts per call

  // LDS read bases (XOR swizzle folded in, loop-invariant)
  int x7 = l16 & 7;
  int ka0 = l16 * 64 + ((quad ^ x7) * 8);            // K: step 0, + nt*1024
  int ka1 = l16 * 64 + (((4 + quad) ^ x7) * 8);      // K: step 1
  int va[2][4];
#pragma unroll
  for (int sub = 0; sub < 2; ++sub)
#pragma unroll
    for (int nt = 0; nt < 4; ++nt)
      va[sub][nt] = l16 * 128 + (((sub * 8 + nt * 2 + (quad >> 1)) ^ l16) * 8)
                    + (quad & 1) * 4;                // V: + dt*2048

  // mask index base (one u64 per (q-row, 64-key tile))
  size_t mi0 = (size_t)(qrowb + l16) * (SEQ / 64);

  bf16x4 ones4;
#pragma unroll
  for (int i = 0; i < 4; ++i) ones4[i] = (short)0x3F80;

  f32x4 zero = {0.f, 0.f, 0.f, 0.f};
  f32x4 accO[4], accRS = zero;
#pragma unroll
  for (int dt = 0; dt < 4; ++dt) accO[dt] = zero;

  // prologue: K(0), V(0) -> buf0
#pragma unroll
  for (int g = 0; g < 2; ++g) {
    gll16(ksrc + (size_t)(g * 64) * DK, &Ks[g * 4096 + sdst]);
    gll16(vsrc + (size_t)(g * 32) * SEQ, &Vs[g * 4096 + sdst]);
  }

  for (int tk = 0; tk < SEQ / 128; ++tk) {
    __syncthreads();   // drains K(tk)+V(tk), issued a full compute phase ago
    if (tk + 1 < SEQ / 128) {
      int nb = ((tk + 1) & 1) * 8192;
      const unsigned short* kn = ksrc + (size_t)(tk + 1) * 128 * DK;
      const unsigned short* vn = vsrc + (tk + 1) * 128;
#pragma unroll
      for (int g = 0; g < 2; ++g) {
        gll16(kn + (size_t)(g * 64) * DK, &Ks[nb + g * 4096 + sdst]);
        gll16(vn + (size_t)(g * 32) * SEQ, &Vs[nb + g * 4096 + sdst]);
      }
    }
    // both sub-tiles' mask words, issued early (S-MFMA hides the latency)
    unsigned long long mA0 = mrow[mi0 + 2 * tk];
    unsigned long long mA1 = mrow[mi0 + 2 * tk + 1];

    int cb = (tk & 1) * 8192;
#pragma unroll
    for (int sub = 0; sub < 2; ++sub) {
      int kb_ = cb + sub * 4096;
      // S^T = K . Q^T : lane's scores -> q = l16, k = nt*16 + quad*4 + r
      f32x4 accS[4];
#pragma unroll
      for (int nt = 0; nt < 4; ++nt) accS[nt] = zero;
      __builtin_amdgcn_s_setprio(1);
#pragma unroll
      for (int step = 0; step < 2; ++step) {
        int ka = step ? ka1 : ka0;
#pragma unroll
        for (int nt = 0; nt < 4; ++nt) {
          bf16x8 kf = *(const bf16x8*)&Ks[kb_ + ka + nt * 1024];
          accS[nt] = __builtin_amdgcn_mfma_f32_16x16x32_bf16(kf, qf[step], accS[nt], 0, 0, 0);
        }
      }
      __builtin_amdgcn_s_setprio(0);

      // masked p = exp2(s), packed in-register into PV A-frags (k = quad*4+j)
      unsigned long long mq = (sub ? mA1 : mA0) >> (quad * 4);
      unsigned mlo = (unsigned)mq, mhi = (unsigned)(mq >> 32);
      bf16x4 ap[4];
#pragma unroll
      for (int nt = 0; nt < 4; ++nt) {
        unsigned w = (nt < 2) ? mlo : mhi;
        unsigned pu[4];
#pragma unroll
        for (int r = 0; r < 4; ++r) {
          float pv = __builtin_amdgcn_exp2f(accS[nt][r]);
          int msk = ((int)(w << (31 - ((nt & 1) * 16 + r)))) >> 31;
          pu[r] = __builtin_bit_cast(unsigned, pv) & (unsigned)msk;
        }
        i32x2 wv;
        wv[0] = pk2u(pu[0], pu[1]);
        wv[1] = pk2u(pu[2], pu[3]);
        ap[nt] = __builtin_bit_cast(bf16x4, wv);
      }

      // row sums + O += P V on the MFMA pipe
      __builtin_amdgcn_s_setprio(1);
#pragma unroll
      for (int nt = 0; nt < 4; ++nt)
        accRS = mfma16(ap[nt], ones4, accRS);
#pragma unroll
      for (int nt = 0; nt < 4; ++nt) {
        int vb_ = cb + va[sub][nt];
#pragma unroll
        for (int dt = 0; dt < 4; ++dt) {
          bf16x4 vf = *(const bf16x4*)&Vs[vb_ + dt * 2048];
          accO[dt] = mfma16(ap[nt], vf, accO[dt]);
        }
      }
      __builtin_amdgcn_s_setprio(0);
    }
  }

#pragma unroll
  for (int r = 0; r < 4; ++r) {
    float sden = accRS[r];
    float inv = sden > 0.f ? 1.f / sden : 0.f;
    int row = qrowb + quad * 4 + r;
    size_t ob = ((size_t)b * SEQ + row) * D_MODEL + (size_t)h * DK;
    for (int dt = 0; dt < 4; ++dt)
      attb[ob + dt * 16 + l16] = f2b_rhu(accO[dt][r] * inv);
  }
}

extern "C" void kernel_launch(void* const* d_in, const int* in_sizes, int n_in,
                              void* d_out, int out_size, void* d_ws, size_t ws_size,
                              hipStream_t stream) {
  (void)in_sizes; (void)n_in; (void)out_size; (void)ws_size;
  const float* q    = (const float*)d_in[0];
  const float* k    = (const float*)d_in[1];
  const float* v    = (const float*)d_in[2];
  const int*   mask = (const int*)d_in[3];
  const float* wq   = (const float*)d_in[4];
  const float* bq   = (const float*)d_in[5];
  const float* wk   = (const float*)d_in[6];
  const float* wv   = (const float*)d_in[7];
  const float* bv   = (const float*)d_in[8];
  const float* wf   = (const float*)d_in[9];
  const float* bf   = (const float*)d_in[10];

  char* ws = (char*)d_ws;
  unsigned short* wft  = (unsigned short*)(ws + 0);          // 2 MiB, live till end
  unsigned short* wqt  = (unsigned short*)(ws + 2097152);    // 2 MiB
  unsigned short* wkt  = (unsigned short*)(ws + 4194304);    // 2 MiB
  unsigned short* wvt  = (unsigned short*)(ws + 6291456);    // 2 MiB
  unsigned short* attb = (unsigned short*)(ws + 2097152);    // 8 MiB alias
  unsigned short* qhp  = (unsigned short*)(ws + 10485760);   // 8 MiB
  unsigned short* khp  = (unsigned short*)(ws + 18874368);   // 8 MiB
  unsigned short* vtp  = (unsigned short*)(ws + 27262976);   // 8 MiB
  unsigned long long* mbits = (unsigned long long*)(ws + 35651584); // 1 MiB
  unsigned short* vb   = (unsigned short*)(ws + 36700160);   // 8 MiB
  unsigned short* qb   = (unsigned short*)d_out;             // 8 MiB (d_out scratch)
  unsigned short* kb   = (unsigned short*)d_out + 4194304;   // 8 MiB

  hipLaunchKernelGGL(prep_kernel, dim3(15360), dim3(256), 0, stream,
                     q, k, v, qb, kb, vb,
                     wq, wk, wv, wf, wqt, wkt, wvt, wft, mask, mbits);
  hipLaunchKernelGGL(gemm_qkv_kernel, dim3(768), dim3(256), 0, stream,
                     qb, kb, vb, wqt, wkt, wvt, bq, bv, qhp, khp, vtp);
  hipLaunchKernelGGL(attn_kernel, dim3(512), dim3(512), 0, stream,
                     qhp, khp, vtp, mbits, attb);
  hipLaunchKernelGGL(gemm_out_kernel, dim3(1024), dim3(256), 0, stream,
                     attb, wft, bf, (float*)d_out);
}